// Round 2
// baseline (339.659 us; speedup 1.0000x reference)
//
#include <hip/hip_runtime.h>
#include <cstdint>
#include <cstddef>

typedef __attribute__((ext_vector_type(8))) __bf16 bf16x8;
typedef __attribute__((ext_vector_type(8))) unsigned short us8;
typedef __attribute__((ext_vector_type(4))) unsigned short us4;
typedef __attribute__((ext_vector_type(4))) float f32x4;

#define DEVI static __device__ __forceinline__

DEVI unsigned short f2bf(float f) {
  union { float f; unsigned u; } v; v.f = f;
  unsigned r = v.u + 0x7fffu + ((v.u >> 16) & 1u);
  return (unsigned short)(r >> 16);
}

DEVI f32x4 mfma16(us8 a, us8 b, f32x4 c) {
  return __builtin_amdgcn_mfma_f32_16x16x32_bf16(
      __builtin_bit_cast(bf16x8, a), __builtin_bit_cast(bf16x8, b), c, 0, 0, 0);
}

DEVI f32x4 fzero4() { f32x4 v = {0.f, 0.f, 0.f, 0.f}; return v; }

// global -> LDS direct copy, 16 B per lane. LDS base must be wave-uniform;
// HW writes lds_base + lane*16. Global address is per-lane.
DEVI void gload16(const unsigned short* g, unsigned short* l) {
  __builtin_amdgcn_global_load_lds(
      (const __attribute__((address_space(1))) unsigned int*)g,
      (__attribute__((address_space(3))) unsigned int*)l, 16, 0, 0);
}

// ---------------------------------------------------------------------------
// Weight transpose + fp32->bf16 cast: w[K][N] -> wt[N][K]
// ---------------------------------------------------------------------------
__global__ __launch_bounds__(256)
void transpose_w(const float* __restrict__ w, unsigned short* __restrict__ wt,
                 int K, int N) {
  __shared__ unsigned short tile[64][65];
  const int t = threadIdx.x;
  const int kb = blockIdx.x * 64, nb = blockIdx.y * 64;
#pragma unroll
  for (int i = 0; i < 4; ++i) {
    int r = i * 16 + (t >> 4);
    int c = (t & 15) * 4;
    float4 v = *(const float4*)(w + (size_t)(kb + r) * N + nb + c);
    tile[r][c + 0] = f2bf(v.x);
    tile[r][c + 1] = f2bf(v.y);
    tile[r][c + 2] = f2bf(v.z);
    tile[r][c + 3] = f2bf(v.w);
  }
  __syncthreads();
#pragma unroll
  for (int i = 0; i < 4; ++i) {
    int n = i * 16 + (t >> 4);
    int k = (t & 15) * 4;
    us4 o;
    o[0] = tile[k + 0][n];
    o[1] = tile[k + 1][n];
    o[2] = tile[k + 2][n];
    o[3] = tile[k + 3][n];
    *(us4*)(wt + (size_t)(nb + n) * K + kb + k) = o;
  }
}

// ---------------------------------------------------------------------------
// LayerNorm over C=1024, fp32 in -> bf16 out. One block per row, 256 threads.
// ---------------------------------------------------------------------------
__global__ __launch_bounds__(256)
void ln_kernel(const float* __restrict__ x, const float* __restrict__ g,
               const float* __restrict__ b, unsigned short* __restrict__ o) {
  const int row = blockIdx.x;
  const int tid = threadIdx.x;
  const float* xr = x + (size_t)row * 1024;
  float4 v = *(const float4*)(xr + tid * 4);
  float s = v.x + v.y + v.z + v.w;
  float sq = v.x * v.x + v.y * v.y + v.z * v.z + v.w * v.w;
#pragma unroll
  for (int m = 1; m < 64; m <<= 1) {
    s += __shfl_xor(s, m, 64);
    sq += __shfl_xor(sq, m, 64);
  }
  __shared__ float ss[4], ssq[4];
  const int wid = tid >> 6, lane = tid & 63;
  if (lane == 0) { ss[wid] = s; ssq[wid] = sq; }
  __syncthreads();
  s = ss[0] + ss[1] + ss[2] + ss[3];
  sq = ssq[0] + ssq[1] + ssq[2] + ssq[3];
  const float mu = s * (1.f / 1024.f);
  const float var = sq * (1.f / 1024.f) - mu * mu;
  const float rstd = rsqrtf(var + 1e-5f);
  const int c = tid * 4;
  float4 gv = *(const float4*)(g + c);
  float4 bv = *(const float4*)(b + c);
  us4 ov;
  ov[0] = f2bf((v.x - mu) * rstd * gv.x + bv.x);
  ov[1] = f2bf((v.y - mu) * rstd * gv.y + bv.y);
  ov[2] = f2bf((v.z - mu) * rstd * gv.z + bv.z);
  ov[3] = f2bf((v.w - mu) * rstd * gv.w + bv.w);
  *(us4*)(o + (size_t)row * 1024 + c) = ov;
}

// ---------------------------------------------------------------------------
// DynamicPosBias MLP: 3969 rows, pd=64, out 16 heads -> posT[16][3969] (f32).
// One wave per row.
// ---------------------------------------------------------------------------
DEVI float pos_layer(float p, const float* __restrict__ g,
                     const float* __restrict__ be, const float* __restrict__ w,
                     const float* __restrict__ bb, int lane) {
  float s = p, sq = p * p;
#pragma unroll
  for (int m = 1; m < 64; m <<= 1) {
    s += __shfl_xor(s, m, 64);
    sq += __shfl_xor(sq, m, 64);
  }
  float mu = s * (1.f / 64.f);
  float var = sq * (1.f / 64.f) - mu * mu;
  float rstd = rsqrtf(var + 1e-5f);
  float y = fmaxf((p - mu) * rstd * g[lane] + be[lane], 0.f);
  float o = bb[lane];
  for (int k = 0; k < 64; ++k) {
    float yk = __shfl(y, k, 64);
    o += yk * w[k * 64 + lane];
  }
  return o;
}

__global__ __launch_bounds__(256)
void pos_mlp(const float* __restrict__ pp_w, const float* __restrict__ pp_b,
             const float* __restrict__ g1, const float* __restrict__ b1,
             const float* __restrict__ w1, const float* __restrict__ bb1,
             const float* __restrict__ g2, const float* __restrict__ b2,
             const float* __restrict__ w2, const float* __restrict__ bb2,
             const float* __restrict__ g3, const float* __restrict__ b3,
             const float* __restrict__ w3, const float* __restrict__ bb3,
             float* __restrict__ posT) {
  const int wid = threadIdx.x >> 6, lane = threadIdx.x & 63;
  const int row = blockIdx.x * 4 + wid;
  if (row >= 3969) return;
  const float bh = (float)(row / 63) - 31.f;
  const float bw = (float)(row % 63) - 31.f;
  float p = bh * pp_w[lane] + bw * pp_w[64 + lane] + pp_b[lane];
  p = pos_layer(p, g1, b1, w1, bb1, lane);
  p = pos_layer(p, g2, b2, w2, bb2, lane);
  float s = p, sq = p * p;
#pragma unroll
  for (int m = 1; m < 64; m <<= 1) {
    s += __shfl_xor(s, m, 64);
    sq += __shfl_xor(sq, m, 64);
  }
  float mu = s * (1.f / 64.f);
  float var = sq * (1.f / 64.f) - mu * mu;
  float rstd = rsqrtf(var + 1e-5f);
  float y = fmaxf((p - mu) * rstd * g3[lane] + b3[lane], 0.f);
  float o = 0.f;
  for (int k = 0; k < 64; ++k) {
    float yk = __shfl(y, k, 64);
    o += yk * w3[k * 16 + (lane & 15)];
  }
  if (lane < 16) posT[(size_t)lane * 3969 + row] = o + bb3[lane];
}

// ---------------------------------------------------------------------------
// GEMM (m97 structure): C[M,N] = A[M,K](bf16) @ Bt[N,K]^T, fp32 accum.
// 128x128 tile, 4 waves 64x64, BK=64, LINEAR LDS + global_load_lds (16B).
// ---------------------------------------------------------------------------
template <bool HAS_BIAS, bool GELU_, bool HAS_RES, bool OUT_BF16, bool OUT_F32>
__global__ __launch_bounds__(256)
void gemm_bt(const unsigned short* __restrict__ A,
             const unsigned short* __restrict__ Bt,
             const float* __restrict__ bias, const float* __restrict__ res,
             unsigned short* __restrict__ outb, float* __restrict__ outf,
             int M, int N, int K) {
  __shared__ unsigned short As[128 * 64];  // [row][64] linear
  __shared__ unsigned short Bs[128 * 64];
  const int tid = threadIdx.x;
  const int lane = tid & 63;
  const int wid = tid >> 6;
  const int lr = lane & 15, lg = lane >> 4;
  const int wr = wid >> 1, wc = wid & 1;
  const int brow = blockIdx.x, bcol = blockIdx.y;

  f32x4 acc[4][4];
#pragma unroll
  for (int mt = 0; mt < 4; ++mt)
#pragma unroll
    for (int nt = 0; nt < 4; ++nt) acc[mt][nt] = fzero4();

  // staging: per call, wave w covers rows [q*32 + w*8, +8) (1 KB), lane l
  // handles row += l>>3, col (l&7)*8 — matches HW's lds_base + lane*16.
  const int srow = wid * 8 + (lane >> 3);
  const int scol = (lane & 7) * 8;
  const unsigned short* Ag = A + (size_t)(brow * 128 + srow) * K + scol;
  const unsigned short* Bg = Bt + (size_t)(bcol * 128 + srow) * K + scol;

  const int nkb = K >> 6;
  for (int kb = 0; kb < nkb; ++kb) {
    __syncthreads();  // previous iteration's LDS readers done
#pragma unroll
    for (int q = 0; q < 4; ++q) {
      gload16(Ag + (size_t)(q * 32) * K + kb * 64, As + (q * 32 + wid * 8) * 64);
      gload16(Bg + (size_t)(q * 32) * K + kb * 64, Bs + (q * 32 + wid * 8) * 64);
    }
    __syncthreads();  // compiler drains vmcnt(0) before barrier
#pragma unroll
    for (int ks = 0; ks < 2; ++ks) {
      us8 af[4], bfr[4];
#pragma unroll
      for (int mt = 0; mt < 4; ++mt)
        af[mt] = *(const us8*)(As + (wr * 64 + mt * 16 + lr) * 64 + ks * 32 + lg * 8);
#pragma unroll
      for (int nt = 0; nt < 4; ++nt)
        bfr[nt] = *(const us8*)(Bs + (wc * 64 + nt * 16 + lr) * 64 + ks * 32 + lg * 8);
#pragma unroll
      for (int mt = 0; mt < 4; ++mt)
#pragma unroll
        for (int nt = 0; nt < 4; ++nt)
          acc[mt][nt] = mfma16(af[mt], bfr[nt], acc[mt][nt]);
    }
  }

#pragma unroll
  for (int mt = 0; mt < 4; ++mt) {
    const int row = brow * 128 + wr * 64 + mt * 16 + 4 * lg;
#pragma unroll
    for (int nt = 0; nt < 4; ++nt) {
      const int col = bcol * 128 + wc * 64 + nt * 16 + lr;
      float bsv = 0.f;
      if constexpr (HAS_BIAS) bsv = bias[col];
#pragma unroll
      for (int i = 0; i < 4; ++i) {
        float v = acc[mt][nt][i] + bsv;
        if constexpr (GELU_) v = 0.5f * v * (1.f + erff(v * 0.70710678118f));
        if constexpr (HAS_RES) v += res[(size_t)(row + i) * N + col];
        if constexpr (OUT_F32) outf[(size_t)(row + i) * N + col] = v;
        if constexpr (OUT_BF16) outb[(size_t)(row + i) * N + col] = f2bf(v);
      }
    }
  }
}

// ---------------------------------------------------------------------------
// Flash attention + dynamic relative-position bias (incremental index).
// qkv layout: [B*N][3072] bf16, q = cols 0..1023, k = 1024..2047, v = 2048+.
// Grid 1024 (XCD-swizzled), 256 threads (4 waves x 16 q-rows), KV tiles 64.
// ---------------------------------------------------------------------------
__global__ __launch_bounds__(256)
void attn_kernel(const unsigned short* __restrict__ qkv,
                 const float* __restrict__ posT,
                 unsigned short* __restrict__ attnb) {
  __shared__ unsigned short Ks[64 * 64];
  __shared__ unsigned short Vt[64 * 64];
  __shared__ unsigned short Ps[64 * 64];

  const int tid = threadIdx.x;
  const int wid = tid >> 6;
  const int lane = tid & 63;
  const int lr = lane & 15;
  const int lg = lane >> 4;

  // bijective XCD swizzle: XCD x handles 128 consecutive original ids ->
  // all 16 q-tiles of a (b,h) pair share one XCD's L2 for K/V.
  const int p = blockIdx.x;
  const int orig = (p & 7) * 128 + (p >> 3);
  const int b = orig >> 8;
  const int h = (orig >> 4) & 15;
  const int qt = orig & 15;

  const int LDQ = 3072;

  // Q fragments (registers for whole KV loop)
  const int qrow = qt * 64 + wid * 16 + lr;
  const unsigned short* qg = qkv + (size_t)(b * 1024 + qrow) * LDQ + h * 64;
  const us8 aq0 = *(const us8*)(qg + lg * 8);
  const us8 aq1 = *(const us8*)(qg + 32 + lg * 8);

  // bias: idx(kt) = idx0 - 126*kt  (hj grows by 2 per 64-col tile)
  const float* pb = posT + (size_t)h * 3969;
  int idx0[4][4];
#pragma unroll
  for (int i = 0; i < 4; ++i) {
    const int qr = qt * 64 + wid * 16 + 4 * lg + i;
    const int hi = qr >> 5, wi = qr & 31;
#pragma unroll
    for (int nt = 0; nt < 4; ++nt) {
      const int kc = nt * 16 + lr;
      idx0[i][nt] = (hi - (kc >> 5) + 31) * 63 + (wi - (kc & 31) + 31);
    }
  }

  float mreg[4], lreg[4];
  f32x4 o[4];
#pragma unroll
  for (int i = 0; i < 4; ++i) { mreg[i] = -1e30f; lreg[i] = 0.f; }
#pragma unroll
  for (int t = 0; t < 4; ++t) o[t] = fzero4();

  // staging thread mapping
  const int ksr = tid >> 2;          // K: tile row 0..63
  const int ksc = (tid & 3) * 16;    // K: d col 0,16,32,48
  const int vk0 = (tid >> 4) * 4;    // V: k rows vk0..vk0+3
  const int vd0 = (tid & 15) * 4;    // V: d cols vd0..vd0+3

  const unsigned short* kbase = qkv + (size_t)(b * 1024) * LDQ + 1024 + h * 64;
  const unsigned short* vbase = qkv + (size_t)(b * 1024) * LDQ + 2048 + h * 64;

  // prefetch tile 0 into registers
  us8 pk0 = *(const us8*)(kbase + (size_t)ksr * LDQ + ksc);
  us8 pk1 = *(const us8*)(kbase + (size_t)ksr * LDQ + ksc + 8);
  us4 pvv[4];
#pragma unroll
  for (int j = 0; j < 4; ++j)
    pvv[j] = *(const us4*)(vbase + (size_t)(vk0 + j) * LDQ + vd0);

  for (int kt = 0; kt < 16; ++kt) {
    __syncthreads();  // previous tile's LDS readers done
    {
      char* ksb = (char*)Ks;
      const int swr = (ksr & 7) << 4;
      *(us8*)(ksb + ksr * 128 + ((ksc * 2) ^ swr)) = pk0;
      *(us8*)(ksb + ksr * 128 + (((ksc + 8) * 2) ^ swr)) = pk1;
      char* vtb = (char*)Vt;
#pragma unroll
      for (int u = 0; u < 4; ++u) {
        us4 w;
        w[0] = pvv[0][u]; w[1] = pvv[1][u]; w[2] = pvv[2][u]; w[3] = pvv[3][u];
        const int d = vd0 + u;
        *(us4*)(vtb + d * 128 + ((vk0 * 2) ^ ((d & 7) << 4))) = w;
      }
    }
    __syncthreads();

    // prefetch next K/V tile (overlaps with all compute below)
    if (kt < 15) {
      const unsigned short* kb2 = kbase + (size_t)((kt + 1) * 64) * LDQ;
      const unsigned short* vb2 = vbase + (size_t)((kt + 1) * 64) * LDQ;
      pk0 = *(const us8*)(kb2 + (size_t)ksr * LDQ + ksc);
      pk1 = *(const us8*)(kb2 + (size_t)ksr * LDQ + ksc + 8);
#pragma unroll
      for (int j = 0; j < 4; ++j)
        pvv[j] = *(const us4*)(vb2 + (size_t)(vk0 + j) * LDQ + vd0);
    }

    // bias gathers (L1-hot 15.9 KB table), issued before the MFMAs
    float bvv[4][4];
    const int koff = kt * 126;
#pragma unroll
    for (int i = 0; i < 4; ++i)
#pragma unroll
      for (int nt = 0; nt < 4; ++nt) bvv[i][nt] = pb[idx0[i][nt] - koff];

    // S = Q K^T
    f32x4 s[4];
#pragma unroll
    for (int nt = 0; nt < 4; ++nt) {
      f32x4 a = fzero4();
      const int kr = nt * 16 + lr;
      const char* ksb = (const char*)Ks;
      const int swz = (kr & 7) << 4;
      us8 bk0 = *(const us8*)(ksb + kr * 128 + (((lg * 8) * 2) ^ swz));
      us8 bk1 = *(const us8*)(ksb + kr * 128 + (((32 + lg * 8) * 2) ^ swz));
      a = mfma16(aq0, bk0, a);
      a = mfma16(aq1, bk1, a);
      s[nt] = a;
    }

    // scale + bias, per-row max
    float pm[4];
#pragma unroll
    for (int i = 0; i < 4; ++i) pm[i] = -1e30f;
#pragma unroll
    for (int nt = 0; nt < 4; ++nt)
#pragma unroll
      for (int i = 0; i < 4; ++i) {
        float sv = s[nt][i] * 0.125f + bvv[i][nt];
        s[nt][i] = sv;
        pm[i] = fmaxf(pm[i], sv);
      }
#pragma unroll
    for (int i = 0; i < 4; ++i)
#pragma unroll
      for (int m = 1; m < 16; m <<= 1)
        pm[i] = fmaxf(pm[i], __shfl_xor(pm[i], m, 64));

    // online softmax update (per-lane partial sum; reduced once at end)
#pragma unroll
    for (int i = 0; i < 4; ++i) {
      const float mn = fmaxf(mreg[i], pm[i]);
      const float f = __expf(mreg[i] - mn);
      float acc = 0.f;
#pragma unroll
      for (int nt = 0; nt < 4; ++nt) {
        float e = __expf(s[nt][i] - mn);
        s[nt][i] = e;
        acc += e;
      }
      lreg[i] = lreg[i] * f + acc;
#pragma unroll
      for (int t = 0; t < 4; ++t) o[t][i] *= f;
      mreg[i] = mn;
    }

    // P -> LDS (wave-private rows), then PV
    {
      char* psb = (char*)Ps;
#pragma unroll
      for (int i = 0; i < 4; ++i) {
        const int prw = wid * 16 + 4 * lg + i;
        const int swz = (prw & 7) << 4;
#pragma unroll
        for (int nt = 0; nt < 4; ++nt)
          *(unsigned short*)(psb + prw * 128 + (((nt * 16 + lr) * 2) ^ swz)) =
              f2bf(s[nt][i]);
      }
      const int prow2 = wid * 16 + lr;
      const int swz2 = (prow2 & 7) << 4;
      us8 pa0 = *(const us8*)(psb + prow2 * 128 + (((lg * 8) * 2) ^ swz2));
      us8 pa1 = *(const us8*)(psb + prow2 * 128 + (((32 + lg * 8) * 2) ^ swz2));
      const char* vtb = (const char*)Vt;
#pragma unroll
      for (int t = 0; t < 4; ++t) {
        const int vr = t * 16 + lr;
        const int swv = (vr & 7) << 4;
        us8 pv0 = *(const us8*)(vtb + vr * 128 + (((lg * 8) * 2) ^ swv));
        us8 pv1 = *(const us8*)(vtb + vr * 128 + (((32 + lg * 8) * 2) ^ swv));
        o[t] = mfma16(pa0, pv0, o[t]);
        o[t] = mfma16(pa1, pv1, o[t]);
      }
    }
  }

  // reduce row-sums across the 16-lane group, normalize, store
#pragma unroll
  for (int i = 0; i < 4; ++i)
#pragma unroll
    for (int m = 1; m < 16; m <<= 1) lreg[i] += __shfl_xor(lreg[i], m, 64);

#pragma unroll
  for (int t = 0; t < 4; ++t)
#pragma unroll
    for (int i = 0; i < 4; ++i) {
      float v = o[t][i] / lreg[i];
      attnb[(size_t)(b * 1024 + qt * 64 + wid * 16 + 4 * lg + i) * 1024 +
            h * 64 + t * 16 + lr] = f2bf(v);
    }
}

// ---------------------------------------------------------------------------
// Launcher
// ---------------------------------------------------------------------------
extern "C" void kernel_launch(void* const* d_in, const int* in_sizes, int n_in,
                              void* d_out, int out_size, void* d_ws,
                              size_t ws_size, hipStream_t stream) {
  const float* x = (const float*)d_in[0];
  const float* n1g = (const float*)d_in[1];
  const float* n1b = (const float*)d_in[2];
  const float* q_w = (const float*)d_in[3];
  const float* kv_w = (const float*)d_in[4];
  const float* proj_w = (const float*)d_in[5];
  const float* proj_b = (const float*)d_in[6];
  const float* pp_w = (const float*)d_in[7];
  const float* pp_b = (const float*)d_in[8];
  const float* ln1g = (const float*)d_in[9];
  const float* ln1b = (const float*)d_in[10];
  const float* lin1w = (const float*)d_in[11];
  const float* lin1b = (const float*)d_in[12];
  const float* ln2g = (const float*)d_in[13];
  const float* ln2b = (const float*)d_in[14];
  const float* lin2w = (const float*)d_in[15];
  const float* lin2b = (const float*)d_in[16];
  const float* ln3g = (const float*)d_in[17];
  const float* ln3b = (const float*)d_in[18];
  const float* lin3w = (const float*)d_in[19];
  const float* lin3b = (const float*)d_in[20];
  const float* n2g = (const float*)d_in[21];
  const float* n2b = (const float*)d_in[22];
  const float* fc1_w = (const float*)d_in[23];
  const float* fc1_b = (const float*)d_in[24];
  const float* fc2_w = (const float*)d_in[25];
  const float* fc2_b = (const float*)d_in[26];
  float* out = (float*)d_out;

  char* ws = (char*)d_ws;
  const size_t MB = 1024ull * 1024ull;
  unsigned short* qkvT = (unsigned short*)(ws + 0 * MB);    // 6 MB [3072][1024]
  unsigned short* projT = (unsigned short*)(ws + 6 * MB);   // 2 MB
  unsigned short* fc1T = (unsigned short*)(ws + 8 * MB);    // 8 MB
  unsigned short* fc2T = (unsigned short*)(ws + 16 * MB);   // 8 MB
  unsigned short* xn = (unsigned short*)(ws + 24 * MB);     // 8 MB
  unsigned short* qkv = (unsigned short*)(ws + 32 * MB);    // 24 MB [4096][3072]
  unsigned short* attnb = (unsigned short*)(ws + 56 * MB);  // 8 MB
  float* x1 = (float*)(ws + 64 * MB);                       // 16 MB
  unsigned short* x2n = (unsigned short*)(ws + 80 * MB);    // 8 MB
  unsigned short* hb = (unsigned short*)(ws + 88 * MB);     // 32 MB
  float* posT = (float*)(ws + 120 * MB);                    // 254 KB

  // weight prep: q rows 0..1023, kv rows 1024..3071 of merged qkvT
  transpose_w<<<dim3(16, 16), 256, 0, stream>>>(q_w, qkvT, 1024, 1024);
  transpose_w<<<dim3(16, 32), 256, 0, stream>>>(
      kv_w, qkvT + (size_t)1024 * 1024, 1024, 2048);
  transpose_w<<<dim3(16, 16), 256, 0, stream>>>(proj_w, projT, 1024, 1024);
  transpose_w<<<dim3(16, 64), 256, 0, stream>>>(fc1_w, fc1T, 1024, 4096);
  transpose_w<<<dim3(64, 16), 256, 0, stream>>>(fc2_w, fc2T, 4096, 1024);

  ln_kernel<<<4096, 256, 0, stream>>>(x, n1g, n1b, xn);
  pos_mlp<<<993, 256, 0, stream>>>(pp_w, pp_b, ln1g, ln1b, lin1w, lin1b, ln2g,
                                   ln2b, lin2w, lin2b, ln3g, ln3b, lin3w,
                                   lin3b, posT);

  // fused qkv projection: [4096][3072]
  gemm_bt<false, false, false, true, false><<<dim3(32, 24), 256, 0, stream>>>(
      xn, qkvT, nullptr, nullptr, qkv, nullptr, 4096, 3072, 1024);

  attn_kernel<<<1024, 256, 0, stream>>>(qkv, posT, attnb);

  // proj + residual(x) -> x1 (fp32)
  gemm_bt<true, false, true, false, true><<<dim3(32, 8), 256, 0, stream>>>(
      attnb, projT, proj_b, x, nullptr, x1, 4096, 1024, 1024);

  ln_kernel<<<4096, 256, 0, stream>>>(x1, n2g, n2b, x2n);

  // fc1 + bias + exact GELU -> hb (bf16)
  gemm_bt<true, true, false, true, false><<<dim3(32, 32), 256, 0, stream>>>(
      x2n, fc1T, fc1_b, nullptr, hb, nullptr, 4096, 4096, 1024);

  // fc2 + bias + residual(x1) -> out (fp32)
  gemm_bt<true, false, true, false, true><<<dim3(32, 8), 256, 0, stream>>>(
      hb, fc2T, fc2_b, x1, nullptr, out, 4096, 1024, 4096);

  (void)in_sizes; (void)n_in; (void)out_size; (void)ws_size;
}

// Round 3
// 326.866 us; speedup vs baseline: 1.0391x; 1.0391x over previous
//
#include <hip/hip_runtime.h>
#include <cstdint>
#include <cstddef>

typedef __attribute__((ext_vector_type(8))) __bf16 bf16x8;
typedef __attribute__((ext_vector_type(8))) unsigned short us8;
typedef __attribute__((ext_vector_type(4))) unsigned short us4;
typedef __attribute__((ext_vector_type(4))) float f32x4;

#define DEVI static __device__ __forceinline__

DEVI unsigned short f2bf(float f) {
  union { float f; unsigned u; } v; v.f = f;
  unsigned r = v.u + 0x7fffu + ((v.u >> 16) & 1u);
  return (unsigned short)(r >> 16);
}

DEVI f32x4 mfma16(us8 a, us8 b, f32x4 c) {
  return __builtin_amdgcn_mfma_f32_16x16x32_bf16(
      __builtin_bit_cast(bf16x8, a), __builtin_bit_cast(bf16x8, b), c, 0, 0, 0);
}

DEVI f32x4 fzero4() { f32x4 v = {0.f, 0.f, 0.f, 0.f}; return v; }

// global -> LDS direct copy, 16 B per lane. LDS base must be wave-uniform;
// HW writes lds_base + lane*16. Global address is per-lane.
DEVI void gload16(const unsigned short* g, unsigned short* l) {
  __builtin_amdgcn_global_load_lds(
      (const __attribute__((address_space(1))) unsigned int*)g,
      (__attribute__((address_space(3))) unsigned int*)l, 16, 0, 0);
}

// ---------------------------------------------------------------------------
// Weight transpose + fp32->bf16 cast: w[K][N] -> wt[N][K]
// ---------------------------------------------------------------------------
__global__ __launch_bounds__(256)
void transpose_w(const float* __restrict__ w, unsigned short* __restrict__ wt,
                 int K, int N) {
  __shared__ unsigned short tile[64][65];
  const int t = threadIdx.x;
  const int kb = blockIdx.x * 64, nb = blockIdx.y * 64;
#pragma unroll
  for (int i = 0; i < 4; ++i) {
    int r = i * 16 + (t >> 4);
    int c = (t & 15) * 4;
    float4 v = *(const float4*)(w + (size_t)(kb + r) * N + nb + c);
    tile[r][c + 0] = f2bf(v.x);
    tile[r][c + 1] = f2bf(v.y);
    tile[r][c + 2] = f2bf(v.z);
    tile[r][c + 3] = f2bf(v.w);
  }
  __syncthreads();
#pragma unroll
  for (int i = 0; i < 4; ++i) {
    int n = i * 16 + (t >> 4);
    int k = (t & 15) * 4;
    us4 o;
    o[0] = tile[k + 0][n];
    o[1] = tile[k + 1][n];
    o[2] = tile[k + 2][n];
    o[3] = tile[k + 3][n];
    *(us4*)(wt + (size_t)(nb + n) * K + kb + k) = o;
  }
}

// ---------------------------------------------------------------------------
// LayerNorm over C=1024, fp32 in -> bf16 out. One block per row, 256 threads.
// ---------------------------------------------------------------------------
__global__ __launch_bounds__(256)
void ln_kernel(const float* __restrict__ x, const float* __restrict__ g,
               const float* __restrict__ b, unsigned short* __restrict__ o) {
  const int row = blockIdx.x;
  const int tid = threadIdx.x;
  const float* xr = x + (size_t)row * 1024;
  float4 v = *(const float4*)(xr + tid * 4);
  float s = v.x + v.y + v.z + v.w;
  float sq = v.x * v.x + v.y * v.y + v.z * v.z + v.w * v.w;
#pragma unroll
  for (int m = 1; m < 64; m <<= 1) {
    s += __shfl_xor(s, m, 64);
    sq += __shfl_xor(sq, m, 64);
  }
  __shared__ float ss[4], ssq[4];
  const int wid = tid >> 6, lane = tid & 63;
  if (lane == 0) { ss[wid] = s; ssq[wid] = sq; }
  __syncthreads();
  s = ss[0] + ss[1] + ss[2] + ss[3];
  sq = ssq[0] + ssq[1] + ssq[2] + ssq[3];
  const float mu = s * (1.f / 1024.f);
  const float var = sq * (1.f / 1024.f) - mu * mu;
  const float rstd = rsqrtf(var + 1e-5f);
  const int c = tid * 4;
  float4 gv = *(const float4*)(g + c);
  float4 bv = *(const float4*)(b + c);
  us4 ov;
  ov[0] = f2bf((v.x - mu) * rstd * gv.x + bv.x);
  ov[1] = f2bf((v.y - mu) * rstd * gv.y + bv.y);
  ov[2] = f2bf((v.z - mu) * rstd * gv.z + bv.z);
  ov[3] = f2bf((v.w - mu) * rstd * gv.w + bv.w);
  *(us4*)(o + (size_t)row * 1024 + c) = ov;
}

// ---------------------------------------------------------------------------
// DynamicPosBias MLP: 3969 rows, pd=64, out 16 heads -> posT[16][3969] (f32).
// One wave per row.
// ---------------------------------------------------------------------------
DEVI float pos_layer(float p, const float* __restrict__ g,
                     const float* __restrict__ be, const float* __restrict__ w,
                     const float* __restrict__ bb, int lane) {
  float s = p, sq = p * p;
#pragma unroll
  for (int m = 1; m < 64; m <<= 1) {
    s += __shfl_xor(s, m, 64);
    sq += __shfl_xor(sq, m, 64);
  }
  float mu = s * (1.f / 64.f);
  float var = sq * (1.f / 64.f) - mu * mu;
  float rstd = rsqrtf(var + 1e-5f);
  float y = fmaxf((p - mu) * rstd * g[lane] + be[lane], 0.f);
  float o = bb[lane];
  for (int k = 0; k < 64; ++k) {
    float yk = __shfl(y, k, 64);
    o += yk * w[k * 64 + lane];
  }
  return o;
}

__global__ __launch_bounds__(256)
void pos_mlp(const float* __restrict__ pp_w, const float* __restrict__ pp_b,
             const float* __restrict__ g1, const float* __restrict__ b1,
             const float* __restrict__ w1, const float* __restrict__ bb1,
             const float* __restrict__ g2, const float* __restrict__ b2,
             const float* __restrict__ w2, const float* __restrict__ bb2,
             const float* __restrict__ g3, const float* __restrict__ b3,
             const float* __restrict__ w3, const float* __restrict__ bb3,
             float* __restrict__ posT) {
  const int wid = threadIdx.x >> 6, lane = threadIdx.x & 63;
  const int row = blockIdx.x * 4 + wid;
  if (row >= 3969) return;
  const float bh = (float)(row / 63) - 31.f;
  const float bw = (float)(row % 63) - 31.f;
  float p = bh * pp_w[lane] + bw * pp_w[64 + lane] + pp_b[lane];
  p = pos_layer(p, g1, b1, w1, bb1, lane);
  p = pos_layer(p, g2, b2, w2, bb2, lane);
  float s = p, sq = p * p;
#pragma unroll
  for (int m = 1; m < 64; m <<= 1) {
    s += __shfl_xor(s, m, 64);
    sq += __shfl_xor(sq, m, 64);
  }
  float mu = s * (1.f / 64.f);
  float var = sq * (1.f / 64.f) - mu * mu;
  float rstd = rsqrtf(var + 1e-5f);
  float y = fmaxf((p - mu) * rstd * g3[lane] + b3[lane], 0.f);
  float o = 0.f;
  for (int k = 0; k < 64; ++k) {
    float yk = __shfl(y, k, 64);
    o += yk * w3[k * 16 + (lane & 15)];
  }
  if (lane < 16) posT[(size_t)lane * 3969 + row] = o + bb3[lane];
}

// ---------------------------------------------------------------------------
// GEMM (m97 structure): C[M,N] = A[M,K](bf16) @ Bt[N,K]^T, fp32 accum.
// Tile BM x 128, 4 waves (each BM/2 x 64), BK=64, linear LDS + global_load_lds.
// BM=128 for large-N GEMMs; BM=64 doubles the grid for narrow-N (proj, fc2)
// so 2 blocks/CU can overlap each other's barrier drains.
// ---------------------------------------------------------------------------
template <int BM, bool HAS_BIAS, bool GELU_, bool HAS_RES, bool OUT_BF16,
          bool OUT_F32>
__global__ __launch_bounds__(256)
void gemm_bt(const unsigned short* __restrict__ A,
             const unsigned short* __restrict__ Bt,
             const float* __restrict__ bias, const float* __restrict__ res,
             unsigned short* __restrict__ outb, float* __restrict__ outf,
             int M, int N, int K) {
  constexpr int MT = BM / 32;  // per-wave m-fragment repeats
  __shared__ unsigned short As[BM * 64];
  __shared__ unsigned short Bs[128 * 64];
  const int tid = threadIdx.x;
  const int lane = tid & 63;
  const int wid = tid >> 6;
  const int lr = lane & 15, lg = lane >> 4;
  const int wr = wid >> 1, wc = wid & 1;
  const int brow = blockIdx.x, bcol = blockIdx.y;

  f32x4 acc[MT][4];
#pragma unroll
  for (int mt = 0; mt < MT; ++mt)
#pragma unroll
    for (int nt = 0; nt < 4; ++nt) acc[mt][nt] = fzero4();

  const int srow = wid * 8 + (lane >> 3);
  const int scol = (lane & 7) * 8;
  const unsigned short* Ag = A + (size_t)(brow * BM + srow) * K + scol;
  const unsigned short* Bg = Bt + (size_t)(bcol * 128 + srow) * K + scol;

  const int nkb = K >> 6;
  for (int kb = 0; kb < nkb; ++kb) {
    __syncthreads();  // previous iteration's LDS readers done
#pragma unroll
    for (int q = 0; q < BM / 32; ++q)
      gload16(Ag + (size_t)(q * 32) * K + kb * 64, As + (q * 32 + wid * 8) * 64);
#pragma unroll
    for (int q = 0; q < 4; ++q)
      gload16(Bg + (size_t)(q * 32) * K + kb * 64, Bs + (q * 32 + wid * 8) * 64);
    __syncthreads();  // compiler drains vmcnt(0) before barrier
#pragma unroll
    for (int ks = 0; ks < 2; ++ks) {
      us8 af[MT], bfr[4];
#pragma unroll
      for (int mt = 0; mt < MT; ++mt)
        af[mt] = *(const us8*)(As + (wr * (BM / 2) + mt * 16 + lr) * 64 +
                               ks * 32 + lg * 8);
#pragma unroll
      for (int nt = 0; nt < 4; ++nt)
        bfr[nt] =
            *(const us8*)(Bs + (wc * 64 + nt * 16 + lr) * 64 + ks * 32 + lg * 8);
#pragma unroll
      for (int mt = 0; mt < MT; ++mt)
#pragma unroll
        for (int nt = 0; nt < 4; ++nt)
          acc[mt][nt] = mfma16(af[mt], bfr[nt], acc[mt][nt]);
    }
  }

#pragma unroll
  for (int mt = 0; mt < MT; ++mt) {
    const int row = brow * BM + wr * (BM / 2) + mt * 16 + 4 * lg;
#pragma unroll
    for (int nt = 0; nt < 4; ++nt) {
      const int col = bcol * 128 + wc * 64 + nt * 16 + lr;
      float bsv = 0.f;
      if constexpr (HAS_BIAS) bsv = bias[col];
#pragma unroll
      for (int i = 0; i < 4; ++i) {
        float v = acc[mt][nt][i] + bsv;
        if constexpr (GELU_) v = 0.5f * v * (1.f + erff(v * 0.70710678118f));
        if constexpr (HAS_RES) v += res[(size_t)(row + i) * N + col];
        if constexpr (OUT_F32) outf[(size_t)(row + i) * N + col] = v;
        if constexpr (OUT_BF16) outb[(size_t)(row + i) * N + col] = f2bf(v);
      }
    }
  }
}

// ---------------------------------------------------------------------------
// Flash attention + dynamic relative-position bias (incremental index).
// qkv layout: [B*N][3072] bf16, q = cols 0..1023, k = 1024..2047, v = 2048+.
// Grid 1024 (XCD-swizzled), 256 threads (4 waves x 16 q-rows), KV tiles 64.
// ---------------------------------------------------------------------------
__global__ __launch_bounds__(256)
void attn_kernel(const unsigned short* __restrict__ qkv,
                 const float* __restrict__ posT,
                 unsigned short* __restrict__ attnb) {
  __shared__ unsigned short Ks[64 * 64];
  __shared__ unsigned short Vt[64 * 64];
  __shared__ unsigned short Ps[64 * 64];

  const int tid = threadIdx.x;
  const int wid = tid >> 6;
  const int lane = tid & 63;
  const int lr = lane & 15;
  const int lg = lane >> 4;

  // bijective XCD swizzle: XCD x handles 128 consecutive original ids ->
  // all 16 q-tiles of a (b,h) pair share one XCD's L2 for K/V.
  const int p = blockIdx.x;
  const int orig = (p & 7) * 128 + (p >> 3);
  const int b = orig >> 8;
  const int h = (orig >> 4) & 15;
  const int qt = orig & 15;

  const int LDQ = 3072;

  // Q fragments (registers for whole KV loop)
  const int qrow = qt * 64 + wid * 16 + lr;
  const unsigned short* qg = qkv + (size_t)(b * 1024 + qrow) * LDQ + h * 64;
  const us8 aq0 = *(const us8*)(qg + lg * 8);
  const us8 aq1 = *(const us8*)(qg + 32 + lg * 8);

  // bias: idx(kt) = idx0 - 126*kt  (hj grows by 2 per 64-col tile)
  const float* pb = posT + (size_t)h * 3969;
  int idx0[4][4];
#pragma unroll
  for (int i = 0; i < 4; ++i) {
    const int qr = qt * 64 + wid * 16 + 4 * lg + i;
    const int hi = qr >> 5, wi = qr & 31;
#pragma unroll
    for (int nt = 0; nt < 4; ++nt) {
      const int kc = nt * 16 + lr;
      idx0[i][nt] = (hi - (kc >> 5) + 31) * 63 + (wi - (kc & 31) + 31);
    }
  }

  float mreg[4], lreg[4];
  f32x4 o[4];
#pragma unroll
  for (int i = 0; i < 4; ++i) { mreg[i] = -1e30f; lreg[i] = 0.f; }
#pragma unroll
  for (int t = 0; t < 4; ++t) o[t] = fzero4();

  // staging thread mapping
  const int ksr = tid >> 2;          // K: tile row 0..63
  const int ksc = (tid & 3) * 16;    // K: d col 0,16,32,48
  const int vk0 = (tid >> 4) * 4;    // V: k rows vk0..vk0+3
  const int vd0 = (tid & 15) * 4;    // V: d cols vd0..vd0+3

  const unsigned short* kbase = qkv + (size_t)(b * 1024) * LDQ + 1024 + h * 64;
  const unsigned short* vbase = qkv + (size_t)(b * 1024) * LDQ + 2048 + h * 64;

  // prefetch tile 0 into registers
  us8 pk0 = *(const us8*)(kbase + (size_t)ksr * LDQ + ksc);
  us8 pk1 = *(const us8*)(kbase + (size_t)ksr * LDQ + ksc + 8);
  us4 pvv[4];
#pragma unroll
  for (int j = 0; j < 4; ++j)
    pvv[j] = *(const us4*)(vbase + (size_t)(vk0 + j) * LDQ + vd0);

  for (int kt = 0; kt < 16; ++kt) {
    __syncthreads();  // previous tile's LDS readers done
    {
      char* ksb = (char*)Ks;
      const int swr = (ksr & 7) << 4;
      *(us8*)(ksb + ksr * 128 + ((ksc * 2) ^ swr)) = pk0;
      *(us8*)(ksb + ksr * 128 + (((ksc + 8) * 2) ^ swr)) = pk1;
      char* vtb = (char*)Vt;
#pragma unroll
      for (int u = 0; u < 4; ++u) {
        us4 w;
        w[0] = pvv[0][u]; w[1] = pvv[1][u]; w[2] = pvv[2][u]; w[3] = pvv[3][u];
        const int d = vd0 + u;
        *(us4*)(vtb + d * 128 + ((vk0 * 2) ^ ((d & 7) << 4))) = w;
      }
    }
    __syncthreads();

    // prefetch next K/V tile (overlaps with all compute below)
    if (kt < 15) {
      const unsigned short* kb2 = kbase + (size_t)((kt + 1) * 64) * LDQ;
      const unsigned short* vb2 = vbase + (size_t)((kt + 1) * 64) * LDQ;
      pk0 = *(const us8*)(kb2 + (size_t)ksr * LDQ + ksc);
      pk1 = *(const us8*)(kb2 + (size_t)ksr * LDQ + ksc + 8);
#pragma unroll
      for (int j = 0; j < 4; ++j)
        pvv[j] = *(const us4*)(vb2 + (size_t)(vk0 + j) * LDQ + vd0);
    }

    // bias gathers (L1-hot 15.9 KB table), issued before the MFMAs
    float bvv[4][4];
    const int koff = kt * 126;
#pragma unroll
    for (int i = 0; i < 4; ++i)
#pragma unroll
      for (int nt = 0; nt < 4; ++nt) bvv[i][nt] = pb[idx0[i][nt] - koff];

    // S = Q K^T
    f32x4 s[4];
#pragma unroll
    for (int nt = 0; nt < 4; ++nt) {
      f32x4 a = fzero4();
      const int kr = nt * 16 + lr;
      const char* ksb = (const char*)Ks;
      const int swz = (kr & 7) << 4;
      us8 bk0 = *(const us8*)(ksb + kr * 128 + (((lg * 8) * 2) ^ swz));
      us8 bk1 = *(const us8*)(ksb + kr * 128 + (((32 + lg * 8) * 2) ^ swz));
      a = mfma16(aq0, bk0, a);
      a = mfma16(aq1, bk1, a);
      s[nt] = a;
    }

    // scale + bias, per-row max
    float pm[4];
#pragma unroll
    for (int i = 0; i < 4; ++i) pm[i] = -1e30f;
#pragma unroll
    for (int nt = 0; nt < 4; ++nt)
#pragma unroll
      for (int i = 0; i < 4; ++i) {
        float sv = s[nt][i] * 0.125f + bvv[i][nt];
        s[nt][i] = sv;
        pm[i] = fmaxf(pm[i], sv);
      }
#pragma unroll
    for (int i = 0; i < 4; ++i)
#pragma unroll
      for (int m = 1; m < 16; m <<= 1)
        pm[i] = fmaxf(pm[i], __shfl_xor(pm[i], m, 64));

    // online softmax update (per-lane partial sum; reduced once at end)
#pragma unroll
    for (int i = 0; i < 4; ++i) {
      const float mn = fmaxf(mreg[i], pm[i]);
      const float f = __expf(mreg[i] - mn);
      float acc = 0.f;
#pragma unroll
      for (int nt = 0; nt < 4; ++nt) {
        float e = __expf(s[nt][i] - mn);
        s[nt][i] = e;
        acc += e;
      }
      lreg[i] = lreg[i] * f + acc;
#pragma unroll
      for (int t = 0; t < 4; ++t) o[t][i] *= f;
      mreg[i] = mn;
    }

    // P -> LDS (wave-private rows), then PV
    {
      char* psb = (char*)Ps;
#pragma unroll
      for (int i = 0; i < 4; ++i) {
        const int prw = wid * 16 + 4 * lg + i;
        const int swz = (prw & 7) << 4;
#pragma unroll
        for (int nt = 0; nt < 4; ++nt)
          *(unsigned short*)(psb + prw * 128 + (((nt * 16 + lr) * 2) ^ swz)) =
              f2bf(s[nt][i]);
      }
      const int prow2 = wid * 16 + lr;
      const int swz2 = (prow2 & 7) << 4;
      us8 pa0 = *(const us8*)(psb + prow2 * 128 + (((lg * 8) * 2) ^ swz2));
      us8 pa1 = *(const us8*)(psb + prow2 * 128 + (((32 + lg * 8) * 2) ^ swz2));
      const char* vtb = (const char*)Vt;
#pragma unroll
      for (int t = 0; t < 4; ++t) {
        const int vr = t * 16 + lr;
        const int swv = (vr & 7) << 4;
        us8 pv0 = *(const us8*)(vtb + vr * 128 + (((lg * 8) * 2) ^ swv));
        us8 pv1 = *(const us8*)(vtb + vr * 128 + (((32 + lg * 8) * 2) ^ swv));
        o[t] = mfma16(pa0, pv0, o[t]);
        o[t] = mfma16(pa1, pv1, o[t]);
      }
    }
  }

  // reduce row-sums across the 16-lane group, normalize, store
#pragma unroll
  for (int i = 0; i < 4; ++i)
#pragma unroll
    for (int m = 1; m < 16; m <<= 1) lreg[i] += __shfl_xor(lreg[i], m, 64);

#pragma unroll
  for (int t = 0; t < 4; ++t)
#pragma unroll
    for (int i = 0; i < 4; ++i) {
      float v = o[t][i] / lreg[i];
      attnb[(size_t)(b * 1024 + qt * 64 + wid * 16 + 4 * lg + i) * 1024 +
            h * 64 + t * 16 + lr] = f2bf(v);
    }
}

// ---------------------------------------------------------------------------
// Launcher
// ---------------------------------------------------------------------------
extern "C" void kernel_launch(void* const* d_in, const int* in_sizes, int n_in,
                              void* d_out, int out_size, void* d_ws,
                              size_t ws_size, hipStream_t stream) {
  const float* x = (const float*)d_in[0];
  const float* n1g = (const float*)d_in[1];
  const float* n1b = (const float*)d_in[2];
  const float* q_w = (const float*)d_in[3];
  const float* kv_w = (const float*)d_in[4];
  const float* proj_w = (const float*)d_in[5];
  const float* proj_b = (const float*)d_in[6];
  const float* pp_w = (const float*)d_in[7];
  const float* pp_b = (const float*)d_in[8];
  const float* ln1g = (const float*)d_in[9];
  const float* ln1b = (const float*)d_in[10];
  const float* lin1w = (const float*)d_in[11];
  const float* lin1b = (const float*)d_in[12];
  const float* ln2g = (const float*)d_in[13];
  const float* ln2b = (const float*)d_in[14];
  const float* lin2w = (const float*)d_in[15];
  const float* lin2b = (const float*)d_in[16];
  const float* ln3g = (const float*)d_in[17];
  const float* ln3b = (const float*)d_in[18];
  const float* lin3w = (const float*)d_in[19];
  const float* lin3b = (const float*)d_in[20];
  const float* n2g = (const float*)d_in[21];
  const float* n2b = (const float*)d_in[22];
  const float* fc1_w = (const float*)d_in[23];
  const float* fc1_b = (const float*)d_in[24];
  const float* fc2_w = (const float*)d_in[25];
  const float* fc2_b = (const float*)d_in[26];
  float* out = (float*)d_out;

  char* ws = (char*)d_ws;
  const size_t MB = 1024ull * 1024ull;
  unsigned short* qkvT = (unsigned short*)(ws + 0 * MB);    // 6 MB [3072][1024]
  unsigned short* projT = (unsigned short*)(ws + 6 * MB);   // 2 MB
  unsigned short* fc1T = (unsigned short*)(ws + 8 * MB);    // 8 MB
  unsigned short* fc2T = (unsigned short*)(ws + 16 * MB);   // 8 MB
  unsigned short* xn = (unsigned short*)(ws + 24 * MB);     // 8 MB
  unsigned short* qkv = (unsigned short*)(ws + 32 * MB);    // 24 MB [4096][3072]
  unsigned short* attnb = (unsigned short*)(ws + 56 * MB);  // 8 MB
  float* x1 = (float*)(ws + 64 * MB);                       // 16 MB
  unsigned short* x2n = (unsigned short*)(ws + 80 * MB);    // 8 MB
  unsigned short* hb = (unsigned short*)(ws + 88 * MB);     // 32 MB
  float* posT = (float*)(ws + 120 * MB);                    // 254 KB

  // weight prep: q rows 0..1023, kv rows 1024..3071 of merged qkvT
  transpose_w<<<dim3(16, 16), 256, 0, stream>>>(q_w, qkvT, 1024, 1024);
  transpose_w<<<dim3(16, 32), 256, 0, stream>>>(
      kv_w, qkvT + (size_t)1024 * 1024, 1024, 2048);
  transpose_w<<<dim3(16, 16), 256, 0, stream>>>(proj_w, projT, 1024, 1024);
  transpose_w<<<dim3(16, 64), 256, 0, stream>>>(fc1_w, fc1T, 1024, 4096);
  transpose_w<<<dim3(64, 16), 256, 0, stream>>>(fc2_w, fc2T, 4096, 1024);

  ln_kernel<<<4096, 256, 0, stream>>>(x, n1g, n1b, xn);
  pos_mlp<<<993, 256, 0, stream>>>(pp_w, pp_b, ln1g, ln1b, lin1w, lin1b, ln2g,
                                   ln2b, lin2w, lin2b, ln3g, ln3b, lin3w,
                                   lin3b, posT);

  // fused qkv projection: [4096][3072]
  gemm_bt<128, false, false, false, true, false>
      <<<dim3(32, 24), 256, 0, stream>>>(xn, qkvT, nullptr, nullptr, qkv,
                                         nullptr, 4096, 3072, 1024);

  attn_kernel<<<1024, 256, 0, stream>>>(qkv, posT, attnb);

  // proj + residual(x) -> x1 (fp32)  [BM=64: 512 blocks, 2/CU]
  gemm_bt<64, true, false, true, false, true>
      <<<dim3(64, 8), 256, 0, stream>>>(attnb, projT, proj_b, x, nullptr, x1,
                                        4096, 1024, 1024);

  ln_kernel<<<4096, 256, 0, stream>>>(x1, n2g, n2b, x2n);

  // fc1 + bias + exact GELU -> hb (bf16)
  gemm_bt<128, true, true, false, true, false>
      <<<dim3(32, 32), 256, 0, stream>>>(x2n, fc1T, fc1_b, nullptr, hb,
                                         nullptr, 4096, 4096, 1024);

  // fc2 + bias + residual(x1) -> out (fp32)  [BM=64: 512 blocks, 2/CU]
  gemm_bt<64, true, false, true, false, true>
      <<<dim3(64, 8), 256, 0, stream>>>(hb, fc2T, fc2_b, x1, nullptr, out,
                                        4096, 1024, 4096);

  (void)in_sizes; (void)n_in; (void)out_size; (void)ws_size;
}

// Round 4
// 300.171 us; speedup vs baseline: 1.1316x; 1.0889x over previous
//
#include <hip/hip_runtime.h>
#include <cstdint>
#include <cstddef>

typedef __attribute__((ext_vector_type(8))) __bf16 bf16x8;
typedef __attribute__((ext_vector_type(8))) unsigned short us8;
typedef __attribute__((ext_vector_type(4))) unsigned short us4;
typedef __attribute__((ext_vector_type(4))) float f32x4;
typedef __attribute__((ext_vector_type(16))) float f32x16;

#define DEVI static __device__ __forceinline__

DEVI unsigned short f2bf(float f) {
  union { float f; unsigned u; } v; v.f = f;
  unsigned r = v.u + 0x7fffu + ((v.u >> 16) & 1u);
  return (unsigned short)(r >> 16);
}

DEVI f32x4 mfma16(us8 a, us8 b, f32x4 c) {
  return __builtin_amdgcn_mfma_f32_16x16x32_bf16(
      __builtin_bit_cast(bf16x8, a), __builtin_bit_cast(bf16x8, b), c, 0, 0, 0);
}

DEVI f32x16 mfma32(us8 a, us8 b, f32x16 c) {
  return __builtin_amdgcn_mfma_f32_32x32x16_bf16(
      __builtin_bit_cast(bf16x8, a), __builtin_bit_cast(bf16x8, b), c, 0, 0, 0);
}

DEVI f32x4 fzero4() { f32x4 v = {0.f, 0.f, 0.f, 0.f}; return v; }

// v_cvt_pk_bf16_f32: two f32 -> packed 2x bf16 (RNE)
DEVI unsigned pkbf(float lo, float hi) {
  unsigned r;
  asm("v_cvt_pk_bf16_f32 %0, %1, %2" : "=v"(r) : "v"(lo), "v"(hi));
  return r;
}

// v_permlane32_swap_b32: new_x = [x.lo | y.lo], new_y = [x.hi | y.hi]
DEVI void pswap(unsigned& x, unsigned& y) {
  asm volatile("v_permlane32_swap_b32 %0, %1" : "+v"(x), "+v"(y));
}

// global -> LDS direct copy, 16 B per lane.
DEVI void gload16(const unsigned short* g, unsigned short* l) {
  __builtin_amdgcn_global_load_lds(
      (const __attribute__((address_space(1))) unsigned int*)g,
      (__attribute__((address_space(3))) unsigned int*)l, 16, 0, 0);
}

// ---------------------------------------------------------------------------
// Weight transpose + fp32->bf16 cast: w[K][N] -> wt[N][K]
// ---------------------------------------------------------------------------
__global__ __launch_bounds__(256)
void transpose_w(const float* __restrict__ w, unsigned short* __restrict__ wt,
                 int K, int N) {
  __shared__ unsigned short tile[64][65];
  const int t = threadIdx.x;
  const int kb = blockIdx.x * 64, nb = blockIdx.y * 64;
#pragma unroll
  for (int i = 0; i < 4; ++i) {
    int r = i * 16 + (t >> 4);
    int c = (t & 15) * 4;
    float4 v = *(const float4*)(w + (size_t)(kb + r) * N + nb + c);
    tile[r][c + 0] = f2bf(v.x);
    tile[r][c + 1] = f2bf(v.y);
    tile[r][c + 2] = f2bf(v.z);
    tile[r][c + 3] = f2bf(v.w);
  }
  __syncthreads();
#pragma unroll
  for (int i = 0; i < 4; ++i) {
    int n = i * 16 + (t >> 4);
    int k = (t & 15) * 4;
    us4 o;
    o[0] = tile[k + 0][n];
    o[1] = tile[k + 1][n];
    o[2] = tile[k + 2][n];
    o[3] = tile[k + 3][n];
    *(us4*)(wt + (size_t)(nb + n) * K + kb + k) = o;
  }
}

// ---------------------------------------------------------------------------
// LayerNorm over C=1024, fp32 in -> bf16 out.
// ---------------------------------------------------------------------------
__global__ __launch_bounds__(256)
void ln_kernel(const float* __restrict__ x, const float* __restrict__ g,
               const float* __restrict__ b, unsigned short* __restrict__ o) {
  const int row = blockIdx.x;
  const int tid = threadIdx.x;
  const float* xr = x + (size_t)row * 1024;
  float4 v = *(const float4*)(xr + tid * 4);
  float s = v.x + v.y + v.z + v.w;
  float sq = v.x * v.x + v.y * v.y + v.z * v.z + v.w * v.w;
#pragma unroll
  for (int m = 1; m < 64; m <<= 1) {
    s += __shfl_xor(s, m, 64);
    sq += __shfl_xor(sq, m, 64);
  }
  __shared__ float ss[4], ssq[4];
  const int wid = tid >> 6, lane = tid & 63;
  if (lane == 0) { ss[wid] = s; ssq[wid] = sq; }
  __syncthreads();
  s = ss[0] + ss[1] + ss[2] + ss[3];
  sq = ssq[0] + ssq[1] + ssq[2] + ssq[3];
  const float mu = s * (1.f / 1024.f);
  const float var = sq * (1.f / 1024.f) - mu * mu;
  const float rstd = rsqrtf(var + 1e-5f);
  const int c = tid * 4;
  float4 gv = *(const float4*)(g + c);
  float4 bv = *(const float4*)(b + c);
  us4 ov;
  ov[0] = f2bf((v.x - mu) * rstd * gv.x + bv.x);
  ov[1] = f2bf((v.y - mu) * rstd * gv.y + bv.y);
  ov[2] = f2bf((v.z - mu) * rstd * gv.z + bv.z);
  ov[3] = f2bf((v.w - mu) * rstd * gv.w + bv.w);
  *(us4*)(o + (size_t)row * 1024 + c) = ov;
}

// ---------------------------------------------------------------------------
// DynamicPosBias MLP -> posT[16][3969] (f32). One wave per row.
// ---------------------------------------------------------------------------
DEVI float pos_layer(float p, const float* __restrict__ g,
                     const float* __restrict__ be, const float* __restrict__ w,
                     const float* __restrict__ bb, int lane) {
  float s = p, sq = p * p;
#pragma unroll
  for (int m = 1; m < 64; m <<= 1) {
    s += __shfl_xor(s, m, 64);
    sq += __shfl_xor(sq, m, 64);
  }
  float mu = s * (1.f / 64.f);
  float var = sq * (1.f / 64.f) - mu * mu;
  float rstd = rsqrtf(var + 1e-5f);
  float y = fmaxf((p - mu) * rstd * g[lane] + be[lane], 0.f);
  float o = bb[lane];
  for (int k = 0; k < 64; ++k) {
    float yk = __shfl(y, k, 64);
    o += yk * w[k * 64 + lane];
  }
  return o;
}

__global__ __launch_bounds__(256)
void pos_mlp(const float* __restrict__ pp_w, const float* __restrict__ pp_b,
             const float* __restrict__ g1, const float* __restrict__ b1,
             const float* __restrict__ w1, const float* __restrict__ bb1,
             const float* __restrict__ g2, const float* __restrict__ b2,
             const float* __restrict__ w2, const float* __restrict__ bb2,
             const float* __restrict__ g3, const float* __restrict__ b3,
             const float* __restrict__ w3, const float* __restrict__ bb3,
             float* __restrict__ posT) {
  const int wid = threadIdx.x >> 6, lane = threadIdx.x & 63;
  const int row = blockIdx.x * 4 + wid;
  if (row >= 3969) return;
  const float bh = (float)(row / 63) - 31.f;
  const float bw = (float)(row % 63) - 31.f;
  float p = bh * pp_w[lane] + bw * pp_w[64 + lane] + pp_b[lane];
  p = pos_layer(p, g1, b1, w1, bb1, lane);
  p = pos_layer(p, g2, b2, w2, bb2, lane);
  float s = p, sq = p * p;
#pragma unroll
  for (int m = 1; m < 64; m <<= 1) {
    s += __shfl_xor(s, m, 64);
    sq += __shfl_xor(sq, m, 64);
  }
  float mu = s * (1.f / 64.f);
  float var = sq * (1.f / 64.f) - mu * mu;
  float rstd = rsqrtf(var + 1e-5f);
  float y = fmaxf((p - mu) * rstd * g3[lane] + b3[lane], 0.f);
  float o = 0.f;
  for (int k = 0; k < 64; ++k) {
    float yk = __shfl(y, k, 64);
    o += yk * w3[k * 16 + (lane & 15)];
  }
  if (lane < 16) posT[(size_t)lane * 3969 + row] = o + bb3[lane];
}

// ---------------------------------------------------------------------------
// GEMM (m97 structure): C[M,N] = A[M,K](bf16) @ Bt[N,K]^T, fp32 accum.
// ---------------------------------------------------------------------------
template <int BM, bool HAS_BIAS, bool GELU_, bool HAS_RES, bool OUT_BF16,
          bool OUT_F32>
__global__ __launch_bounds__(256)
void gemm_bt(const unsigned short* __restrict__ A,
             const unsigned short* __restrict__ Bt,
             const float* __restrict__ bias, const float* __restrict__ res,
             unsigned short* __restrict__ outb, float* __restrict__ outf,
             int M, int N, int K) {
  constexpr int MT = BM / 32;
  __shared__ unsigned short As[BM * 64];
  __shared__ unsigned short Bs[128 * 64];
  const int tid = threadIdx.x;
  const int lane = tid & 63;
  const int wid = tid >> 6;
  const int lr = lane & 15, lg = lane >> 4;
  const int wr = wid >> 1, wc = wid & 1;
  const int brow = blockIdx.x, bcol = blockIdx.y;

  f32x4 acc[MT][4];
#pragma unroll
  for (int mt = 0; mt < MT; ++mt)
#pragma unroll
    for (int nt = 0; nt < 4; ++nt) acc[mt][nt] = fzero4();

  const int srow = wid * 8 + (lane >> 3);
  const int scol = (lane & 7) * 8;
  const unsigned short* Ag = A + (size_t)(brow * BM + srow) * K + scol;
  const unsigned short* Bg = Bt + (size_t)(bcol * 128 + srow) * K + scol;

  const int nkb = K >> 6;
  for (int kb = 0; kb < nkb; ++kb) {
    __syncthreads();
#pragma unroll
    for (int q = 0; q < BM / 32; ++q)
      gload16(Ag + (size_t)(q * 32) * K + kb * 64, As + (q * 32 + wid * 8) * 64);
#pragma unroll
    for (int q = 0; q < 4; ++q)
      gload16(Bg + (size_t)(q * 32) * K + kb * 64, Bs + (q * 32 + wid * 8) * 64);
    __syncthreads();
#pragma unroll
    for (int ks = 0; ks < 2; ++ks) {
      us8 af[MT], bfr[4];
#pragma unroll
      for (int mt = 0; mt < MT; ++mt)
        af[mt] = *(const us8*)(As + (wr * (BM / 2) + mt * 16 + lr) * 64 +
                               ks * 32 + lg * 8);
#pragma unroll
      for (int nt = 0; nt < 4; ++nt)
        bfr[nt] =
            *(const us8*)(Bs + (wc * 64 + nt * 16 + lr) * 64 + ks * 32 + lg * 8);
#pragma unroll
      for (int mt = 0; mt < MT; ++mt)
#pragma unroll
        for (int nt = 0; nt < 4; ++nt)
          acc[mt][nt] = mfma16(af[mt], bfr[nt], acc[mt][nt]);
    }
  }

#pragma unroll
  for (int mt = 0; mt < MT; ++mt) {
    const int row = brow * BM + wr * (BM / 2) + mt * 16 + 4 * lg;
#pragma unroll
    for (int nt = 0; nt < 4; ++nt) {
      const int col = bcol * 128 + wc * 64 + nt * 16 + lr;
      float bsv = 0.f;
      if constexpr (HAS_BIAS) bsv = bias[col];
#pragma unroll
      for (int i = 0; i < 4; ++i) {
        float v = acc[mt][nt][i] + bsv;
        if constexpr (GELU_) v = 0.5f * v * (1.f + erff(v * 0.70710678118f));
        if constexpr (HAS_RES) v += res[(size_t)(row + i) * N + col];
        if constexpr (OUT_F32) outf[(size_t)(row + i) * N + col] = v;
        if constexpr (OUT_BF16) outb[(size_t)(row + i) * N + col] = f2bf(v);
      }
    }
  }
}

// ---------------------------------------------------------------------------
// Flash attention, swapped-QK^T 32x32 structure (T12) + dynamic pos bias.
// Block: 4 waves x 32 q-rows = 128 q. Grid 512 (XCD-swizzled). KV tiles 64.
// S^T = mfma32(K, Q): lane owns q = lane&31; k lane-local -> in-register
// softmax; P -> bf16 via cvt_pk + permlane32_swap feeds PV B-operand.
// O^T = mfma32(V^T, P^T).
// ---------------------------------------------------------------------------
__global__ __launch_bounds__(256)
void attn_kernel(const unsigned short* __restrict__ qkv,
                 const float* __restrict__ posT,
                 unsigned short* __restrict__ attnb) {
  __shared__ unsigned short Ks[64 * 64];  // [k][d], XOR-swizzled rows
  __shared__ unsigned short Vt[64 * 64];  // [d][k], XOR-swizzled rows

  const int tid = threadIdx.x;
  const int wid = tid >> 6;
  const int lane = tid & 63;
  const int ql = lane & 31;  // q column owned by this lane
  const int hi = lane >> 5;  // lane half

  // XCD swizzle: 512 blocks, 64 consecutive orig ids per XCD.
  const int p = blockIdx.x;
  const int orig = (p & 7) * 64 + (p >> 3);
  const int b = orig >> 7;
  const int h = (orig >> 3) & 15;
  const int qt = orig & 7;

  const int LDQ = 3072;
  const int qg = qt * 128 + wid * 32 + ql;  // global q row

  // Q fragments (B-operand of swapped QK^T): lane holds Q[qg][db*16+8*hi+j]
  us8 qf[4];
  const unsigned short* qptr =
      qkv + (size_t)(b * 1024 + qg) * LDQ + h * 64 + 8 * hi;
#pragma unroll
  for (int db = 0; db < 4; ++db) qf[db] = *(const us8*)(qptr + db * 16);

  // bias: idx(q,k) = rb_q - 63*kh - roff, roff compile-time per reg
  const float* pb = posT + (size_t)h * 3969;
  const int rb_q = ((qg >> 5) + 31) * 63 + (qg & 31) + 31 - 4 * hi;

  f32x16 oacc[2];
#pragma unroll
  for (int r = 0; r < 16; ++r) { oacc[0][r] = 0.f; oacc[1][r] = 0.f; }
  float mreg = -1e30f, lsum = 0.f;

  // staging maps
  const int ksr = tid >> 2;        // K row 0..63
  const int ksc = (tid & 3) * 16;  // K d-col
  const int vk0 = (tid >> 4) * 4;  // V k rows
  const int vd0 = (tid & 15) * 4;  // V d cols

  const unsigned short* kbase = qkv + (size_t)(b * 1024) * LDQ + 1024 + h * 64;
  const unsigned short* vbase = qkv + (size_t)(b * 1024) * LDQ + 2048 + h * 64;

  us8 pk0 = *(const us8*)(kbase + (size_t)ksr * LDQ + ksc);
  us8 pk1 = *(const us8*)(kbase + (size_t)ksr * LDQ + ksc + 8);
  us4 pvv[4];
#pragma unroll
  for (int j = 0; j < 4; ++j)
    pvv[j] = *(const us4*)(vbase + (size_t)(vk0 + j) * LDQ + vd0);

  for (int kt = 0; kt < 16; ++kt) {
    __syncthreads();
    {
      char* ksb = (char*)Ks;
      const int swr = (ksr & 7) << 4;
      *(us8*)(ksb + ksr * 128 + ((ksc * 2) ^ swr)) = pk0;
      *(us8*)(ksb + ksr * 128 + (((ksc + 8) * 2) ^ swr)) = pk1;
      char* vtb = (char*)Vt;
#pragma unroll
      for (int u = 0; u < 4; ++u) {
        us4 w;
        w[0] = pvv[0][u]; w[1] = pvv[1][u]; w[2] = pvv[2][u]; w[3] = pvv[3][u];
        const int d = vd0 + u;
        *(us4*)(vtb + d * 128 + ((vk0 * 2) ^ ((d & 7) << 4))) = w;
      }
    }
    __syncthreads();

    // prefetch next tile
    if (kt < 15) {
      const unsigned short* kb2 = kbase + (size_t)((kt + 1) * 64) * LDQ;
      const unsigned short* vb2 = vbase + (size_t)((kt + 1) * 64) * LDQ;
      pk0 = *(const us8*)(kb2 + (size_t)ksr * LDQ + ksc);
      pk1 = *(const us8*)(kb2 + (size_t)ksr * LDQ + ksc + 8);
#pragma unroll
      for (int j = 0; j < 4; ++j)
        pvv[j] = *(const us4*)(vb2 + (size_t)(vk0 + j) * LDQ + vd0);
    }

    // S^T = K @ Q^T : two 32k x 32q tiles
    f32x16 st0, st1;
#pragma unroll
    for (int r = 0; r < 16; ++r) { st0[r] = 0.f; st1[r] = 0.f; }
    const char* ksb = (const char*)Ks;
    const int kswz = (ql & 7) << 4;
    __builtin_amdgcn_s_setprio(1);
#pragma unroll
    for (int db = 0; db < 4; ++db) {
      const int coff = (db * 32 + 16 * hi) ^ kswz;
      us8 kf0 = *(const us8*)(ksb + ql * 128 + coff);
      us8 kf1 = *(const us8*)(ksb + (32 + ql) * 128 + coff);
      st0 = mfma32(kf0, qf[db], st0);
      st1 = mfma32(kf1, qf[db], st1);
    }
    __builtin_amdgcn_s_setprio(0);

    // bias + scale; per-lane max over 32 values (tree)
    float sv0[16], sv1[16];
    const float* pb0 = pb + (rb_q - 63 * (2 * kt));
    const float* pb1 = pb0 - 63;
    float mm[16];
#pragma unroll
    for (int r = 0; r < 16; ++r) {
      const int roff = (r & 3) + 8 * (r >> 2);
      float a = st0[r] * 0.125f + pb0[-roff];
      float c = st1[r] * 0.125f + pb1[-roff];
      sv0[r] = a;
      sv1[r] = c;
      mm[r] = fmaxf(a, c);
    }
#pragma unroll
    for (int w = 8; w >= 1; w >>= 1)
#pragma unroll
      for (int r = 0; r < w; ++r) mm[r] = fmaxf(mm[r], mm[r + w]);
    float mx = fmaxf(mreg, mm[0]);
    mx = fmaxf(mx, __shfl_xor(mx, 32, 64));
    const float f = __expf(mreg - mx);
    mreg = mx;

    float ts[16];
#pragma unroll
    for (int r = 0; r < 16; ++r) {
      float e0 = __expf(sv0[r] - mx);
      float e1 = __expf(sv1[r] - mx);
      sv0[r] = e0;
      sv1[r] = e1;
      ts[r] = e0 + e1;
    }
#pragma unroll
    for (int w = 8; w >= 1; w >>= 1)
#pragma unroll
      for (int r = 0; r < w; ++r) ts[r] += ts[r + w];
    lsum = lsum * f + ts[0];
#pragma unroll
    for (int r = 0; r < 16; ++r) { oacc[0][r] *= f; oacc[1][r] *= f; }

    // P fragments (cvt_pk + permlane32_swap) -> PV
    const char* vtb = (const char*)Vt;
    auto pvfrag = [&](const float* sv, int kb) {
      const int B0 = (kb & 1) * 8;
      unsigned a0 = pkbf(sv[B0 + 0], sv[B0 + 1]);
      unsigned a1 = pkbf(sv[B0 + 2], sv[B0 + 3]);
      unsigned b0 = pkbf(sv[B0 + 4], sv[B0 + 5]);
      unsigned b1 = pkbf(sv[B0 + 6], sv[B0 + 7]);
      pswap(a0, b0);
      pswap(a1, b1);
      union { us8 s; unsigned u[4]; } fu;
      fu.u[0] = a0; fu.u[1] = a1; fu.u[2] = b0; fu.u[3] = b1;
      const int coff = (kb * 32 + 16 * hi) ^ kswz;
      us8 vf0 = *(const us8*)(vtb + ql * 128 + coff);
      us8 vf1 = *(const us8*)(vtb + (32 + ql) * 128 + coff);
      __builtin_amdgcn_s_setprio(1);
      oacc[0] = mfma32(vf0, fu.s, oacc[0]);
      oacc[1] = mfma32(vf1, fu.s, oacc[1]);
      __builtin_amdgcn_s_setprio(0);
    };
    pvfrag(sv0, 0);
    pvfrag(sv0, 1);
    pvfrag(sv1, 2);
    pvfrag(sv1, 3);
  }

  // finalize: cross-half sum, normalize, store O^T -> attnb[q][h*64+d]
  lsum += __shfl_xor(lsum, 32, 64);
  const float inv = 1.f / lsum;
  unsigned short* orow = attnb + (size_t)(b * 1024 + qg) * 1024 + h * 64;
#pragma unroll
  for (int dm = 0; dm < 2; ++dm)
#pragma unroll
    for (int r = 0; r < 16; ++r) {
      const int d = dm * 32 + (r & 3) + 8 * (r >> 2) + 4 * hi;
      orow[d] = f2bf(oacc[dm][r] * inv);
    }
}

// ---------------------------------------------------------------------------
// Launcher
// ---------------------------------------------------------------------------
extern "C" void kernel_launch(void* const* d_in, const int* in_sizes, int n_in,
                              void* d_out, int out_size, void* d_ws,
                              size_t ws_size, hipStream_t stream) {
  const float* x = (const float*)d_in[0];
  const float* n1g = (const float*)d_in[1];
  const float* n1b = (const float*)d_in[2];
  const float* q_w = (const float*)d_in[3];
  const float* kv_w = (const float*)d_in[4];
  const float* proj_w = (const float*)d_in[5];
  const float* proj_b = (const float*)d_in[6];
  const float* pp_w = (const float*)d_in[7];
  const float* pp_b = (const float*)d_in[8];
  const float* ln1g = (const float*)d_in[9];
  const float* ln1b = (const float*)d_in[10];
  const float* lin1w = (const float*)d_in[11];
  const float* lin1b = (const float*)d_in[12];
  const float* ln2g = (const float*)d_in[13];
  const float* ln2b = (const float*)d_in[14];
  const float* lin2w = (const float*)d_in[15];
  const float* lin2b = (const float*)d_in[16];
  const float* ln3g = (const float*)d_in[17];
  const float* ln3b = (const float*)d_in[18];
  const float* lin3w = (const float*)d_in[19];
  const float* lin3b = (const float*)d_in[20];
  const float* n2g = (const float*)d_in[21];
  const float* n2b = (const float*)d_in[22];
  const float* fc1_w = (const float*)d_in[23];
  const float* fc1_b = (const float*)d_in[24];
  const float* fc2_w = (const float*)d_in[25];
  const float* fc2_b = (const float*)d_in[26];
  float* out = (float*)d_out;

  char* ws = (char*)d_ws;
  const size_t MB = 1024ull * 1024ull;
  unsigned short* qkvT = (unsigned short*)(ws + 0 * MB);
  unsigned short* projT = (unsigned short*)(ws + 6 * MB);
  unsigned short* fc1T = (unsigned short*)(ws + 8 * MB);
  unsigned short* fc2T = (unsigned short*)(ws + 16 * MB);
  unsigned short* xn = (unsigned short*)(ws + 24 * MB);
  unsigned short* qkv = (unsigned short*)(ws + 32 * MB);
  unsigned short* attnb = (unsigned short*)(ws + 56 * MB);
  float* x1 = (float*)(ws + 64 * MB);
  unsigned short* x2n = (unsigned short*)(ws + 80 * MB);
  unsigned short* hb = (unsigned short*)(ws + 88 * MB);
  float* posT = (float*)(ws + 120 * MB);

  transpose_w<<<dim3(16, 16), 256, 0, stream>>>(q_w, qkvT, 1024, 1024);
  transpose_w<<<dim3(16, 32), 256, 0, stream>>>(
      kv_w, qkvT + (size_t)1024 * 1024, 1024, 2048);
  transpose_w<<<dim3(16, 16), 256, 0, stream>>>(proj_w, projT, 1024, 1024);
  transpose_w<<<dim3(16, 64), 256, 0, stream>>>(fc1_w, fc1T, 1024, 4096);
  transpose_w<<<dim3(64, 16), 256, 0, stream>>>(fc2_w, fc2T, 4096, 1024);

  ln_kernel<<<4096, 256, 0, stream>>>(x, n1g, n1b, xn);
  pos_mlp<<<993, 256, 0, stream>>>(pp_w, pp_b, ln1g, ln1b, lin1w, lin1b, ln2g,
                                   ln2b, lin2w, lin2b, ln3g, ln3b, lin3w,
                                   lin3b, posT);

  gemm_bt<128, false, false, false, true, false>
      <<<dim3(32, 24), 256, 0, stream>>>(xn, qkvT, nullptr, nullptr, qkv,
                                         nullptr, 4096, 3072, 1024);

  attn_kernel<<<512, 256, 0, stream>>>(qkv, posT, attnb);

  gemm_bt<64, true, false, true, false, true>
      <<<dim3(64, 8), 256, 0, stream>>>(attnb, projT, proj_b, x, nullptr, x1,
                                        4096, 1024, 1024);

  ln_kernel<<<4096, 256, 0, stream>>>(x1, n2g, n2b, x2n);

  gemm_bt<128, true, true, false, true, false>
      <<<dim3(32, 32), 256, 0, stream>>>(x2n, fc1T, fc1_b, nullptr, hb,
                                         nullptr, 4096, 4096, 1024);

  gemm_bt<64, true, false, true, false, true>
      <<<dim3(64, 8), 256, 0, stream>>>(hb, fc2T, fc2_b, x1, nullptr, out,
                                        4096, 1024, 4096);

  (void)in_sizes; (void)n_in; (void)out_size; (void)ws_size;
}

// Round 5
// 282.941 us; speedup vs baseline: 1.2005x; 1.0609x over previous
//
#include <hip/hip_runtime.h>
#include <cstdint>
#include <cstddef>

typedef __attribute__((ext_vector_type(8))) __bf16 bf16x8;
typedef __attribute__((ext_vector_type(8))) unsigned short us8;
typedef __attribute__((ext_vector_type(4))) unsigned short us4;
typedef __attribute__((ext_vector_type(4))) float f32x4;
typedef __attribute__((ext_vector_type(16))) float f32x16;

#define DEVI static __device__ __forceinline__

DEVI unsigned short f2bf(float f) {
  union { float f; unsigned u; } v; v.f = f;
  unsigned r = v.u + 0x7fffu + ((v.u >> 16) & 1u);
  return (unsigned short)(r >> 16);
}

DEVI f32x4 mfma16(us8 a, us8 b, f32x4 c) {
  return __builtin_amdgcn_mfma_f32_16x16x32_bf16(
      __builtin_bit_cast(bf16x8, a), __builtin_bit_cast(bf16x8, b), c, 0, 0, 0);
}

DEVI f32x16 mfma32(us8 a, us8 b, f32x16 c) {
  return __builtin_amdgcn_mfma_f32_32x32x16_bf16(
      __builtin_bit_cast(bf16x8, a), __builtin_bit_cast(bf16x8, b), c, 0, 0, 0);
}

DEVI f32x4 fzero4() { f32x4 v = {0.f, 0.f, 0.f, 0.f}; return v; }

// tanh-form GELU: ~9 VALU ops vs erff's ~20+. |err| < 3e-3 abs.
DEVI float gelu_f(float v) {
  float z = 0.7978845608f * v * (1.f + 0.044715f * v * v);
  float e = __expf(2.f * z);         // z>>0: inf -> r=0 -> v; z<<0: 0 -> r=1 -> 0
  float r = 1.f / (e + 1.f);
  return v * (1.f - r);
}

// v_cvt_pk_bf16_f32: two f32 -> packed 2x bf16 (RNE)
DEVI unsigned pkbf(float lo, float hi) {
  unsigned r;
  asm("v_cvt_pk_bf16_f32 %0, %1, %2" : "=v"(r) : "v"(lo), "v"(hi));
  return r;
}

// v_permlane32_swap_b32: new_x = [x.lo | y.lo], new_y = [x.hi | y.hi]
DEVI void pswap(unsigned& x, unsigned& y) {
  asm volatile("v_permlane32_swap_b32 %0, %1" : "+v"(x), "+v"(y));
}

// global -> LDS direct copy, 16 B per lane.
DEVI void gload16(const unsigned short* g, unsigned short* l) {
  __builtin_amdgcn_global_load_lds(
      (const __attribute__((address_space(1))) unsigned int*)g,
      (__attribute__((address_space(3))) unsigned int*)l, 16, 0, 0);
}

// ---------------------------------------------------------------------------
// Weight transpose + fp32->bf16 cast: w[K][N] -> wt[N][K]
// ---------------------------------------------------------------------------
__global__ __launch_bounds__(256)
void transpose_w(const float* __restrict__ w, unsigned short* __restrict__ wt,
                 int K, int N) {
  __shared__ unsigned short tile[64][65];
  const int t = threadIdx.x;
  const int kb = blockIdx.x * 64, nb = blockIdx.y * 64;
#pragma unroll
  for (int i = 0; i < 4; ++i) {
    int r = i * 16 + (t >> 4);
    int c = (t & 15) * 4;
    float4 v = *(const float4*)(w + (size_t)(kb + r) * N + nb + c);
    tile[r][c + 0] = f2bf(v.x);
    tile[r][c + 1] = f2bf(v.y);
    tile[r][c + 2] = f2bf(v.z);
    tile[r][c + 3] = f2bf(v.w);
  }
  __syncthreads();
#pragma unroll
  for (int i = 0; i < 4; ++i) {
    int n = i * 16 + (t >> 4);
    int k = (t & 15) * 4;
    us4 o;
    o[0] = tile[k + 0][n];
    o[1] = tile[k + 1][n];
    o[2] = tile[k + 2][n];
    o[3] = tile[k + 3][n];
    *(us4*)(wt + (size_t)(nb + n) * K + kb + k) = o;
  }
}

// ---------------------------------------------------------------------------
// LayerNorm over C=1024, fp32 in -> bf16 out.
// ---------------------------------------------------------------------------
__global__ __launch_bounds__(256)
void ln_kernel(const float* __restrict__ x, const float* __restrict__ g,
               const float* __restrict__ b, unsigned short* __restrict__ o) {
  const int row = blockIdx.x;
  const int tid = threadIdx.x;
  const float* xr = x + (size_t)row * 1024;
  float4 v = *(const float4*)(xr + tid * 4);
  float s = v.x + v.y + v.z + v.w;
  float sq = v.x * v.x + v.y * v.y + v.z * v.z + v.w * v.w;
#pragma unroll
  for (int m = 1; m < 64; m <<= 1) {
    s += __shfl_xor(s, m, 64);
    sq += __shfl_xor(sq, m, 64);
  }
  __shared__ float ss[4], ssq[4];
  const int wid = tid >> 6, lane = tid & 63;
  if (lane == 0) { ss[wid] = s; ssq[wid] = sq; }
  __syncthreads();
  s = ss[0] + ss[1] + ss[2] + ss[3];
  sq = ssq[0] + ssq[1] + ssq[2] + ssq[3];
  const float mu = s * (1.f / 1024.f);
  const float var = sq * (1.f / 1024.f) - mu * mu;
  const float rstd = rsqrtf(var + 1e-5f);
  const int c = tid * 4;
  float4 gv = *(const float4*)(g + c);
  float4 bv = *(const float4*)(b + c);
  us4 ov;
  ov[0] = f2bf((v.x - mu) * rstd * gv.x + bv.x);
  ov[1] = f2bf((v.y - mu) * rstd * gv.y + bv.y);
  ov[2] = f2bf((v.z - mu) * rstd * gv.z + bv.z);
  ov[3] = f2bf((v.w - mu) * rstd * gv.w + bv.w);
  *(us4*)(o + (size_t)row * 1024 + c) = ov;
}

// ---------------------------------------------------------------------------
// DynamicPosBias MLP -> posT[16][3969] (f32). One wave per row.
// ---------------------------------------------------------------------------
DEVI float pos_layer(float p, const float* __restrict__ g,
                     const float* __restrict__ be, const float* __restrict__ w,
                     const float* __restrict__ bb, int lane) {
  float s = p, sq = p * p;
#pragma unroll
  for (int m = 1; m < 64; m <<= 1) {
    s += __shfl_xor(s, m, 64);
    sq += __shfl_xor(sq, m, 64);
  }
  float mu = s * (1.f / 64.f);
  float var = sq * (1.f / 64.f) - mu * mu;
  float rstd = rsqrtf(var + 1e-5f);
  float y = fmaxf((p - mu) * rstd * g[lane] + be[lane], 0.f);
  float o = bb[lane];
  for (int k = 0; k < 64; ++k) {
    float yk = __shfl(y, k, 64);
    o += yk * w[k * 64 + lane];
  }
  return o;
}

__global__ __launch_bounds__(256)
void pos_mlp(const float* __restrict__ pp_w, const float* __restrict__ pp_b,
             const float* __restrict__ g1, const float* __restrict__ b1,
             const float* __restrict__ w1, const float* __restrict__ bb1,
             const float* __restrict__ g2, const float* __restrict__ b2,
             const float* __restrict__ w2, const float* __restrict__ bb2,
             const float* __restrict__ g3, const float* __restrict__ b3,
             const float* __restrict__ w3, const float* __restrict__ bb3,
             float* __restrict__ posT) {
  const int wid = threadIdx.x >> 6, lane = threadIdx.x & 63;
  const int row = blockIdx.x * 4 + wid;
  if (row >= 3969) return;
  const float bh = (float)(row / 63) - 31.f;
  const float bw = (float)(row % 63) - 31.f;
  float p = bh * pp_w[lane] + bw * pp_w[64 + lane] + pp_b[lane];
  p = pos_layer(p, g1, b1, w1, bb1, lane);
  p = pos_layer(p, g2, b2, w2, bb2, lane);
  float s = p, sq = p * p;
#pragma unroll
  for (int m = 1; m < 64; m <<= 1) {
    s += __shfl_xor(s, m, 64);
    sq += __shfl_xor(sq, m, 64);
  }
  float mu = s * (1.f / 64.f);
  float var = sq * (1.f / 64.f) - mu * mu;
  float rstd = rsqrtf(var + 1e-5f);
  float y = fmaxf((p - mu) * rstd * g3[lane] + b3[lane], 0.f);
  float o = 0.f;
  for (int k = 0; k < 64; ++k) {
    float yk = __shfl(y, k, 64);
    o += yk * w3[k * 16 + (lane & 15)];
  }
  if (lane < 16) posT[(size_t)lane * 3969 + row] = o + bb3[lane];
}

// ---------------------------------------------------------------------------
// GEMM, 2-phase double-buffered (T3-minimum): C[M,N] = A @ Bt^T, fp32 accum.
// Tile BM x 128, 4 waves, BK=64. Stage tile kb+1 via global_load_lds BEFORE
// computing tile kb; one barrier per K-step (drains vmcnt+lgkm).
// ---------------------------------------------------------------------------
template <int BM, bool HAS_BIAS, bool GELU_, bool HAS_RES, bool OUT_BF16,
          bool OUT_F32>
__global__ __launch_bounds__(256)
void gemm_bt(const unsigned short* __restrict__ A,
             const unsigned short* __restrict__ Bt,
             const float* __restrict__ bias, const float* __restrict__ res,
             unsigned short* __restrict__ outb, float* __restrict__ outf,
             int M, int N, int K) {
  constexpr int MT = BM / 32;
  __shared__ unsigned short As[2][BM * 64];
  __shared__ unsigned short Bs[2][128 * 64];
  const int tid = threadIdx.x;
  const int lane = tid & 63;
  const int wid = tid >> 6;
  const int lr = lane & 15, lg = lane >> 4;
  const int wr = wid >> 1, wc = wid & 1;
  const int brow = blockIdx.x, bcol = blockIdx.y;

  f32x4 acc[MT][4];
#pragma unroll
  for (int mt = 0; mt < MT; ++mt)
#pragma unroll
    for (int nt = 0; nt < 4; ++nt) acc[mt][nt] = fzero4();

  const int srow = wid * 8 + (lane >> 3);
  const int scol = (lane & 7) * 8;
  const unsigned short* Ag = A + (size_t)(brow * BM + srow) * K + scol;
  const unsigned short* Bg = Bt + (size_t)(bcol * 128 + srow) * K + scol;

  auto stage = [&](int buf, int kb) {
#pragma unroll
    for (int q = 0; q < BM / 32; ++q)
      gload16(Ag + (size_t)(q * 32) * K + kb * 64,
              &As[buf][(q * 32 + wid * 8) * 64]);
#pragma unroll
    for (int q = 0; q < 4; ++q)
      gload16(Bg + (size_t)(q * 32) * K + kb * 64,
              &Bs[buf][(q * 32 + wid * 8) * 64]);
  };

  const int nkb = K >> 6;
  stage(0, 0);
  __syncthreads();  // tile 0 resident
  int cur = 0;
  for (int kb = 0; kb < nkb; ++kb) {
    if (kb + 1 < nkb) stage(cur ^ 1, kb + 1);  // async, overlaps compute
#pragma unroll
    for (int ks = 0; ks < 2; ++ks) {
      us8 af[MT], bfr[4];
#pragma unroll
      for (int mt = 0; mt < MT; ++mt)
        af[mt] = *(const us8*)(&As[cur][(wr * (BM / 2) + mt * 16 + lr) * 64 +
                                        ks * 32 + lg * 8]);
#pragma unroll
      for (int nt = 0; nt < 4; ++nt)
        bfr[nt] = *(const us8*)(&Bs[cur][(wc * 64 + nt * 16 + lr) * 64 +
                                         ks * 32 + lg * 8]);
      __builtin_amdgcn_s_setprio(1);
#pragma unroll
      for (int mt = 0; mt < MT; ++mt)
#pragma unroll
        for (int nt = 0; nt < 4; ++nt)
          acc[mt][nt] = mfma16(af[mt], bfr[nt], acc[mt][nt]);
      __builtin_amdgcn_s_setprio(0);
    }
    __syncthreads();  // drains staged loads; next tile ready
    cur ^= 1;
  }

#pragma unroll
  for (int mt = 0; mt < MT; ++mt) {
    const int row = brow * BM + wr * (BM / 2) + mt * 16 + 4 * lg;
#pragma unroll
    for (int nt = 0; nt < 4; ++nt) {
      const int col = bcol * 128 + wc * 64 + nt * 16 + lr;
      float bsv = 0.f;
      if constexpr (HAS_BIAS) bsv = bias[col];
#pragma unroll
      for (int i = 0; i < 4; ++i) {
        float v = acc[mt][nt][i] + bsv;
        if constexpr (GELU_) v = gelu_f(v);
        if constexpr (HAS_RES) v += res[(size_t)(row + i) * N + col];
        if constexpr (OUT_F32) outf[(size_t)(row + i) * N + col] = v;
        if constexpr (OUT_BF16) outb[(size_t)(row + i) * N + col] = f2bf(v);
      }
    }
  }
}

// ---------------------------------------------------------------------------
// Flash attention, swapped-QK^T 32x32 structure (T12) + dynamic pos bias.
// ---------------------------------------------------------------------------
__global__ __launch_bounds__(256)
void attn_kernel(const unsigned short* __restrict__ qkv,
                 const float* __restrict__ posT,
                 unsigned short* __restrict__ attnb) {
  __shared__ unsigned short Ks[64 * 64];  // [k][d], XOR-swizzled rows
  __shared__ unsigned short Vt[64 * 64];  // [d][k], XOR-swizzled rows

  const int tid = threadIdx.x;
  const int wid = tid >> 6;
  const int lane = tid & 63;
  const int ql = lane & 31;
  const int hi = lane >> 5;

  const int p = blockIdx.x;
  const int orig = (p & 7) * 64 + (p >> 3);
  const int b = orig >> 7;
  const int h = (orig >> 3) & 15;
  const int qt = orig & 7;

  const int LDQ = 3072;
  const int qg = qt * 128 + wid * 32 + ql;

  us8 qf[4];
  const unsigned short* qptr =
      qkv + (size_t)(b * 1024 + qg) * LDQ + h * 64 + 8 * hi;
#pragma unroll
  for (int db = 0; db < 4; ++db) qf[db] = *(const us8*)(qptr + db * 16);

  const float* pb = posT + (size_t)h * 3969;
  const int rb_q = ((qg >> 5) + 31) * 63 + (qg & 31) + 31 - 4 * hi;

  f32x16 oacc[2];
#pragma unroll
  for (int r = 0; r < 16; ++r) { oacc[0][r] = 0.f; oacc[1][r] = 0.f; }
  float mreg = -1e30f, lsum = 0.f;

  const int ksr = tid >> 2;
  const int ksc = (tid & 3) * 16;
  const int vk0 = (tid >> 4) * 4;
  const int vd0 = (tid & 15) * 4;

  const unsigned short* kbase = qkv + (size_t)(b * 1024) * LDQ + 1024 + h * 64;
  const unsigned short* vbase = qkv + (size_t)(b * 1024) * LDQ + 2048 + h * 64;

  us8 pk0 = *(const us8*)(kbase + (size_t)ksr * LDQ + ksc);
  us8 pk1 = *(const us8*)(kbase + (size_t)ksr * LDQ + ksc + 8);
  us4 pvv[4];
#pragma unroll
  for (int j = 0; j < 4; ++j)
    pvv[j] = *(const us4*)(vbase + (size_t)(vk0 + j) * LDQ + vd0);

  for (int kt = 0; kt < 16; ++kt) {
    __syncthreads();
    {
      char* ksb = (char*)Ks;
      const int swr = (ksr & 7) << 4;
      *(us8*)(ksb + ksr * 128 + ((ksc * 2) ^ swr)) = pk0;
      *(us8*)(ksb + ksr * 128 + (((ksc + 8) * 2) ^ swr)) = pk1;
      char* vtb = (char*)Vt;
#pragma unroll
      for (int u = 0; u < 4; ++u) {
        us4 w;
        w[0] = pvv[0][u]; w[1] = pvv[1][u]; w[2] = pvv[2][u]; w[3] = pvv[3][u];
        const int d = vd0 + u;
        *(us4*)(vtb + d * 128 + ((vk0 * 2) ^ ((d & 7) << 4))) = w;
      }
    }
    __syncthreads();

    if (kt < 15) {
      const unsigned short* kb2 = kbase + (size_t)((kt + 1) * 64) * LDQ;
      const unsigned short* vb2 = vbase + (size_t)((kt + 1) * 64) * LDQ;
      pk0 = *(const us8*)(kb2 + (size_t)ksr * LDQ + ksc);
      pk1 = *(const us8*)(kb2 + (size_t)ksr * LDQ + ksc + 8);
#pragma unroll
      for (int j = 0; j < 4; ++j)
        pvv[j] = *(const us4*)(vb2 + (size_t)(vk0 + j) * LDQ + vd0);
    }

    f32x16 st0, st1;
#pragma unroll
    for (int r = 0; r < 16; ++r) { st0[r] = 0.f; st1[r] = 0.f; }
    const char* ksb = (const char*)Ks;
    const int kswz = (ql & 7) << 4;
    __builtin_amdgcn_s_setprio(1);
#pragma unroll
    for (int db = 0; db < 4; ++db) {
      const int coff = (db * 32 + 16 * hi) ^ kswz;
      us8 kf0 = *(const us8*)(ksb + ql * 128 + coff);
      us8 kf1 = *(const us8*)(ksb + (32 + ql) * 128 + coff);
      st0 = mfma32(kf0, qf[db], st0);
      st1 = mfma32(kf1, qf[db], st1);
    }
    __builtin_amdgcn_s_setprio(0);

    float sv0[16], sv1[16];
    const float* pb0 = pb + (rb_q - 63 * (2 * kt));
    const float* pb1 = pb0 - 63;
    float mm[16];
#pragma unroll
    for (int r = 0; r < 16; ++r) {
      const int roff = (r & 3) + 8 * (r >> 2);
      float a = st0[r] * 0.125f + pb0[-roff];
      float c = st1[r] * 0.125f + pb1[-roff];
      sv0[r] = a;
      sv1[r] = c;
      mm[r] = fmaxf(a, c);
    }
#pragma unroll
    for (int w = 8; w >= 1; w >>= 1)
#pragma unroll
      for (int r = 0; r < w; ++r) mm[r] = fmaxf(mm[r], mm[r + w]);
    float mx = fmaxf(mreg, mm[0]);
    mx = fmaxf(mx, __shfl_xor(mx, 32, 64));
    const float f = __expf(mreg - mx);
    mreg = mx;

    float ts[16];
#pragma unroll
    for (int r = 0; r < 16; ++r) {
      float e0 = __expf(sv0[r] - mx);
      float e1 = __expf(sv1[r] - mx);
      sv0[r] = e0;
      sv1[r] = e1;
      ts[r] = e0 + e1;
    }
#pragma unroll
    for (int w = 8; w >= 1; w >>= 1)
#pragma unroll
      for (int r = 0; r < w; ++r) ts[r] += ts[r + w];
    lsum = lsum * f + ts[0];
#pragma unroll
    for (int r = 0; r < 16; ++r) { oacc[0][r] *= f; oacc[1][r] *= f; }

    const char* vtb = (const char*)Vt;
    auto pvfrag = [&](const float* sv, int kb) {
      const int B0 = (kb & 1) * 8;
      unsigned a0 = pkbf(sv[B0 + 0], sv[B0 + 1]);
      unsigned a1 = pkbf(sv[B0 + 2], sv[B0 + 3]);
      unsigned b0 = pkbf(sv[B0 + 4], sv[B0 + 5]);
      unsigned b1 = pkbf(sv[B0 + 6], sv[B0 + 7]);
      pswap(a0, b0);
      pswap(a1, b1);
      union { us8 s; unsigned u[4]; } fu;
      fu.u[0] = a0; fu.u[1] = a1; fu.u[2] = b0; fu.u[3] = b1;
      const int coff = (kb * 32 + 16 * hi) ^ kswz;
      us8 vf0 = *(const us8*)(vtb + ql * 128 + coff);
      us8 vf1 = *(const us8*)(vtb + (32 + ql) * 128 + coff);
      __builtin_amdgcn_s_setprio(1);
      oacc[0] = mfma32(vf0, fu.s, oacc[0]);
      oacc[1] = mfma32(vf1, fu.s, oacc[1]);
      __builtin_amdgcn_s_setprio(0);
    };
    pvfrag(sv0, 0);
    pvfrag(sv0, 1);
    pvfrag(sv1, 2);
    pvfrag(sv1, 3);
  }

  lsum += __shfl_xor(lsum, 32, 64);
  const float inv = 1.f / lsum;
  unsigned short* orow = attnb + (size_t)(b * 1024 + qg) * 1024 + h * 64;
#pragma unroll
  for (int dm = 0; dm < 2; ++dm)
#pragma unroll
    for (int r = 0; r < 16; ++r) {
      const int d = dm * 32 + (r & 3) + 8 * (r >> 2) + 4 * hi;
      orow[d] = f2bf(oacc[dm][r] * inv);
    }
}

// ---------------------------------------------------------------------------
// Launcher
// ---------------------------------------------------------------------------
extern "C" void kernel_launch(void* const* d_in, const int* in_sizes, int n_in,
                              void* d_out, int out_size, void* d_ws,
                              size_t ws_size, hipStream_t stream) {
  const float* x = (const float*)d_in[0];
  const float* n1g = (const float*)d_in[1];
  const float* n1b = (const float*)d_in[2];
  const float* q_w = (const float*)d_in[3];
  const float* kv_w = (const float*)d_in[4];
  const float* proj_w = (const float*)d_in[5];
  const float* proj_b = (const float*)d_in[6];
  const float* pp_w = (const float*)d_in[7];
  const float* pp_b = (const float*)d_in[8];
  const float* ln1g = (const float*)d_in[9];
  const float* ln1b = (const float*)d_in[10];
  const float* lin1w = (const float*)d_in[11];
  const float* lin1b = (const float*)d_in[12];
  const float* ln2g = (const float*)d_in[13];
  const float* ln2b = (const float*)d_in[14];
  const float* lin2w = (const float*)d_in[15];
  const float* lin2b = (const float*)d_in[16];
  const float* ln3g = (const float*)d_in[17];
  const float* ln3b = (const float*)d_in[18];
  const float* lin3w = (const float*)d_in[19];
  const float* lin3b = (const float*)d_in[20];
  const float* n2g = (const float*)d_in[21];
  const float* n2b = (const float*)d_in[22];
  const float* fc1_w = (const float*)d_in[23];
  const float* fc1_b = (const float*)d_in[24];
  const float* fc2_w = (const float*)d_in[25];
  const float* fc2_b = (const float*)d_in[26];
  float* out = (float*)d_out;

  char* ws = (char*)d_ws;
  const size_t MB = 1024ull * 1024ull;
  unsigned short* qkvT = (unsigned short*)(ws + 0 * MB);
  unsigned short* projT = (unsigned short*)(ws + 6 * MB);
  unsigned short* fc1T = (unsigned short*)(ws + 8 * MB);
  unsigned short* fc2T = (unsigned short*)(ws + 16 * MB);
  unsigned short* xn = (unsigned short*)(ws + 24 * MB);
  unsigned short* qkv = (unsigned short*)(ws + 32 * MB);
  unsigned short* attnb = (unsigned short*)(ws + 56 * MB);
  float* x1 = (float*)(ws + 64 * MB);
  unsigned short* x2n = (unsigned short*)(ws + 80 * MB);
  unsigned short* hb = (unsigned short*)(ws + 88 * MB);
  float* posT = (float*)(ws + 120 * MB);

  transpose_w<<<dim3(16, 16), 256, 0, stream>>>(q_w, qkvT, 1024, 1024);
  transpose_w<<<dim3(16, 32), 256, 0, stream>>>(
      kv_w, qkvT + (size_t)1024 * 1024, 1024, 2048);
  transpose_w<<<dim3(16, 16), 256, 0, stream>>>(proj_w, projT, 1024, 1024);
  transpose_w<<<dim3(16, 64), 256, 0, stream>>>(fc1_w, fc1T, 1024, 4096);
  transpose_w<<<dim3(64, 16), 256, 0, stream>>>(fc2_w, fc2T, 4096, 1024);

  ln_kernel<<<4096, 256, 0, stream>>>(x, n1g, n1b, xn);
  pos_mlp<<<993, 256, 0, stream>>>(pp_w, pp_b, ln1g, ln1b, lin1w, lin1b, ln2g,
                                   ln2b, lin2w, lin2b, ln3g, ln3b, lin3w,
                                   lin3b, posT);

  gemm_bt<128, false, false, false, true, false>
      <<<dim3(32, 24), 256, 0, stream>>>(xn, qkvT, nullptr, nullptr, qkv,
                                         nullptr, 4096, 3072, 1024);

  attn_kernel<<<512, 256, 0, stream>>>(qkv, posT, attnb);

  gemm_bt<64, true, false, true, false, true>
      <<<dim3(64, 8), 256, 0, stream>>>(attnb, projT, proj_b, x, nullptr, x1,
                                        4096, 1024, 1024);

  ln_kernel<<<4096, 256, 0, stream>>>(x1, n2g, n2b, x2n);

  gemm_bt<128, true, true, false, true, false>
      <<<dim3(32, 32), 256, 0, stream>>>(x2n, fc1T, fc1_b, nullptr, hb,
                                         nullptr, 4096, 4096, 1024);

  gemm_bt<64, true, false, true, false, true>
      <<<dim3(64, 8), 256, 0, stream>>>(hb, fc2T, fc2_b, x1, nullptr, out,
                                        4096, 1024, 4096);

  (void)in_sizes; (void)n_in; (void)out_size; (void)ws_size;
}